// Round 9
// baseline (213.690 us; speedup 1.0000x reference)
//
#include <hip/hip_runtime.h>
#include <hip/hip_bf16.h>

#define NB 32
#define NN 1024
#define DINR 144

typedef __attribute__((ext_vector_type(4))) float f4;
typedef __attribute__((ext_vector_type(8))) short s8;

// ws float offsets
#define OFF_B0  (0u)
#define OFF_B1  (1u*NB*64*NN)
#define OFF_C   (2u*NB*64*NN)
#define OFF_UPA (3u*NB*64*NN)                 // B-part partials (ping)
#define OFF_UPB (OFF_UPA + NB*32*1024u)       // B-part partials (pong)
#define OFF_UPC (OFF_UPB + NB*32*1024u)       // A-part partials (static)
#define OFF_UC  (OFF_UPC + NB*32*1024u)       // combined U (per layer)
#define OFF_NS  (OFF_UC + NB*1024u)

static __device__ __forceinline__ unsigned short bf16u(float f) {
  __hip_bfloat16 h = __float2bfloat16(f);
  return *reinterpret_cast<unsigned short*>(&h);
}

// build an 8-bf16 MFMA fragment from 8 consecutive f32 in LDS (16B-aligned)
static __device__ __forceinline__ s8 frag8(const float* p) {
  f4 lo = *reinterpret_cast<const f4*>(p);
  f4 hi = *reinterpret_cast<const f4*>(p + 4);
  union { s8 v; unsigned short u[8]; } F;
  F.u[0] = bf16u(lo[0]); F.u[1] = bf16u(lo[1]);
  F.u[2] = bf16u(lo[2]); F.u[3] = bf16u(lo[3]);
  F.u[4] = bf16u(hi[0]); F.u[5] = bf16u(hi[1]);
  F.u[6] = bf16u(hi[2]); F.u[7] = bf16u(hi[3]);
  return F.v;
}

// ---------------------------------------------------------------------------
// k_init  (unchanged from R8)
// ---------------------------------------------------------------------------
__global__ __launch_bounds__(256) void k_init(
    const float* __restrict__ x, const float* __restrict__ emb,
    float* __restrict__ Bt, float* __restrict__ UpC, float* __restrict__ UpB,
    int* __restrict__ nstar)
{
  __shared__ union {
    unsigned int XT[NN * 8];
    struct {
      float xs[80 * 36];
      float es[512 * 4];
      float as[64 * 36];
    } d;
  } sm;
  int t = threadIdx.x;
  if (blockIdx.x < 1024) {
    int b = blockIdx.x >> 5;
    int ct = blockIdx.x & 31;
    int n0 = ct * 32;
    const float* xb = x + (size_t)b * DINR * NN;
    for (int idx = t; idx < 80 * 32; idx += 256) {
      int row = idx >> 5, col = idx & 31;
      sm.d.xs[row * 36 + col] = xb[row * NN + n0 + col];
    }
    f4* es4 = reinterpret_cast<f4*>(sm.d.es);
    const f4* E4g = reinterpret_cast<const f4*>(emb);
    for (int fj = t; fj < 512; fj += 256) {
      int j = fj >> 3, cc = fj & 7;
      es4[j * 8 + ((cc ^ (j >> 3)) & 7)] = E4g[fj];
    }
    __syncthreads();
    int c = t >> 3, g = t & 7;
    int n = n0 + c;
    bool live = (n < 1008);
    float a[8], bb[8];
    float xa[32];
    #pragma unroll
    for (int cc = 0; cc < 32; cc++) xa[cc] = sm.d.xs[(16 + cc) * 36 + c];
    #pragma unroll
    for (int jj = 0; jj < 8; jj++) {
      int j = g * 8 + jj;
      float acc = 0.f;
      #pragma unroll
      for (int cc = 0; cc < 8; cc++) {
        f4 e = es4[j * 8 + ((cc ^ g) & 7)];
        acc += e[0]*xa[4*cc] + e[1]*xa[4*cc+1] + e[2]*xa[4*cc+2] + e[3]*xa[4*cc+3];
      }
      a[jj] = acc;
    }
    #pragma unroll
    for (int cc = 0; cc < 32; cc++) xa[cc] = sm.d.xs[(48 + cc) * 36 + c];
    #pragma unroll
    for (int jj = 0; jj < 8; jj++) {
      int j = g * 8 + jj;
      float acc = 0.f;
      #pragma unroll
      for (int cc = 0; cc < 8; cc++) {
        f4 e = es4[j * 8 + ((cc ^ g) & 7)];
        acc += e[0]*xa[4*cc] + e[1]*xa[4*cc+1] + e[2]*xa[4*cc+2] + e[3]*xa[4*cc+3];
      }
      bb[jj] = acc;
    }
    f4 v0 = {bb[0], bb[1], bb[2], bb[3]};
    f4 v1 = {bb[4], bb[5], bb[6], bb[7]};
    f4* Bb = reinterpret_cast<f4*>(Bt + ((size_t)b * NN + n) * 64 + g * 8);
    Bb[0] = v0; Bb[1] = v1;
    #pragma unroll
    for (int jj = 0; jj < 8; jj++)
      sm.d.as[(g * 8 + jj) * 36 + c] = live ? a[jj] : 0.f;
    __syncthreads();
    {
      int lane = t & 63, w = t >> 6;
      int r = lane & 15, q = lane >> 4;
      int jw = w * 16;
      s8 af = frag8(&sm.d.as[(jw + r) * 36 + q * 8]);
      s8 bf = frag8(&sm.d.xs[r * 36 + q * 8]);
      f4 acc = {0.f, 0.f, 0.f, 0.f};
      acc = __builtin_amdgcn_mfma_f32_16x16x32_bf16(af, bf, acc, 0, 0, 0);
      float* upc = UpC + ((size_t)(b * 32 + ct)) * 1024;
      #pragma unroll
      for (int reg = 0; reg < 4; reg++)
        upc[(jw + q * 4 + reg) * 16 + r] = acc[reg];
    }
    __syncthreads();
    #pragma unroll
    for (int jj = 0; jj < 8; jj++)
      sm.d.as[(g * 8 + jj) * 36 + c] = live ? bb[jj] : 0.f;
    __syncthreads();
    {
      int lane = t & 63, w = t >> 6;
      int r = lane & 15, q = lane >> 4;
      int jw = w * 16;
      s8 af = frag8(&sm.d.as[(jw + r) * 36 + q * 8]);
      s8 bf = frag8(&sm.d.xs[r * 36 + q * 8]);
      f4 acc = {0.f, 0.f, 0.f, 0.f};
      acc = __builtin_amdgcn_mfma_f32_16x16x32_bf16(af, bf, acc, 0, 0, 0);
      float* upb = UpB + ((size_t)(b * 32 + ct)) * 1024;
      #pragma unroll
      for (int reg = 0; reg < 4; reg++)
        upb[(jw + q * 4 + reg) * 16 + r] = acc[reg];
    }
  } else {
    int a = blockIdx.x - 1024;
    int b = a >> 4;
    int mg = a & 15;
    const float* xb = x + (size_t)b * DINR * NN;
    #pragma unroll
    for (int rep = 0; rep < 4; rep++) {
      int n = t + (rep << 8);
      unsigned int pk[8];
      #pragma unroll
      for (int h = 0; h < 8; h++) {
        unsigned int u0 = __float_as_uint(xb[(2*h) * NN + n]);
        unsigned int u1 = __float_as_uint(xb[(2*h+1) * NN + n]);
        pk[h] = (u0 >> 16) | (u1 & 0xFFFF0000u);
      }
      #pragma unroll
      for (int h = 0; h < 8; h++) sm.XT[n * 8 + h] = pk[h];
    }
    __syncthreads();
    int w = t >> 6;
    int lane = t & 63;
    int r = lane & 15;
    int g = lane >> 4;
    int mt = mg * 64 + w * 16;
    s8 zero8 = {0,0,0,0,0,0,0,0};
    s8 afrag = zero8;
    if (g < 2) afrag = *reinterpret_cast<const s8*>(&sm.XT[(mt + r) * 8 + g * 4]);
    float bestv[4];
    int besti[4];
    #pragma unroll
    for (int j = 0; j < 4; j++) { bestv[j] = -3.4e38f; besti[j] = 0x7FFFFFFF; }
    for (int nt = 0; nt < 63; nt++) {
      s8 bfrag = zero8;
      if (g < 2) bfrag = *reinterpret_cast<const s8*>(&sm.XT[(nt*16 + r) * 8 + g * 4]);
      f4 acc = {0.f, 0.f, 0.f, 0.f};
      acc = __builtin_amdgcn_mfma_f32_16x16x32_bf16(afrag, bfrag, acc, 0, 0, 0);
      int n = nt * 16 + r;
      #pragma unroll
      for (int j = 0; j < 4; j++) {
        float v = acc[j];
        bool better = (v > bestv[j]) || (v == bestv[j] && n < besti[j]);
        if (better) { bestv[j] = v; besti[j] = n; }
      }
    }
    #pragma unroll
    for (int s = 1; s < 16; s <<= 1) {
      #pragma unroll
      for (int j = 0; j < 4; j++) {
        float ov = __shfl_xor(bestv[j], s, 64);
        int   oi = __shfl_xor(besti[j], s, 64);
        bool better = (ov > bestv[j]) || (ov == bestv[j] && oi < besti[j]);
        if (better) { bestv[j] = ov; besti[j] = oi; }
      }
    }
    if (r == 0) {
      #pragma unroll
      for (int j = 0; j < 4; j++)
        nstar[b * NN + mt + g * 4 + j] = besti[j];
    }
  }
}

// ---------------------------------------------------------------------------
// k_comb: Uc[b][j][i] = alpha[l][j] * (sum UpC chunks - sum UpB chunks)
// ---------------------------------------------------------------------------
__global__ __launch_bounds__(256) void k_comb(
    const float* __restrict__ UpC, const float* __restrict__ UpB, int ncb,
    const float* __restrict__ alpha, int l, float* __restrict__ Uc)
{
  int b = blockIdx.x >> 2;
  int idx = ((blockIdx.x & 3) << 8) + threadIdx.x;
  const float* pc = UpC + (size_t)b * 32 * 1024 + idx;
  const float* pb = UpB + (size_t)b * ncb * 1024 + idx;
  float sa = 0.f, sb = 0.f;
  #pragma unroll 8
  for (int ch = 0; ch < 32; ch++) sa += pc[ch * 1024];
  for (int ch = 0; ch < ncb; ch++) sb += pb[ch * 1024];
  Uc[(size_t)b * 1024 + idx] = alpha[l * 64 + (idx >> 4)] * (sa - sb);
}

// ---------------------------------------------------------------------------
// k_update: 512 threads (8 waves), 64-col tiles, wave-uniform j stripe of 8.
// grid 512 = 32 b x 16 tiles. lane=col, wave w owns j in [8w,8w+8).
// __launch_bounds__(512,4): 2 blocks/CU (16 waves/CU), VGPR cap 128 (no spill)
// ---------------------------------------------------------------------------
__global__ __launch_bounds__(512, 4) void k_update(
    const float* __restrict__ x, const float* __restrict__ emb,
    const float* __restrict__ kpp, const float* __restrict__ Uc,
    const int* __restrict__ nstar,
    const float* __restrict__ Cin, size_t cbs, float* __restrict__ Cout,
    const float* __restrict__ Bin, float* __restrict__ Bout,
    float* __restrict__ Upout, int last, float* __restrict__ out)
{
  __shared__ float Lg[64 * 33];   // logit accumulators [col][cat]
  __shared__ float Ws[64 * 68];   // masked Bout rows [j][col], 16B-aligned
  __shared__ float Xf[16 * 68];   // X rows [i][col]
  int t = threadIdx.x;
  int b = blockIdx.x >> 4;
  int mt = blockIdx.x & 15;
  int n0 = mt * 64;
  int lane = t & 63;
  int w = t >> 6;
  int c = lane;
  int m = n0 + c;
  const float* xb = x + (size_t)b * DINR * NN;

  int nst = nstar[b * NN + m];           // prefetch: no dependencies

  for (int i = t; i < 64 * 33; i += 512) Lg[i] = 0.f;
  for (int s = t; s < 16 * 64; s += 512) {
    int i = s >> 6, c0 = s & 63;
    Xf[i * 68 + c0] = xb[i * NN + n0 + c0];
  }
  __syncthreads();

  float X[16];
  #pragma unroll
  for (int i = 0; i < 16; i++) X[i] = Xf[i * 68 + c];

  int jw = __builtin_amdgcn_readfirstlane(w * 8);
  float sc = kpp[0] * (1.0f / 1008.0f);

  // ---- phase A: C update + logit partials (j = jw..jw+7) ----
  {
    float cin[8];
    #pragma unroll
    for (int jj = 0; jj < 8; jj++)
      cin[jj] = Cin[(size_t)b * cbs + (size_t)(jw + jj) * NN + m];
    float cn[8];
    #pragma unroll
    for (int jj = 0; jj < 8; jj++) {
      const float* Ur = Uc + ((size_t)b * 64 + jw + jj) * 16;
      float d = 0.f;
      #pragma unroll
      for (int i = 0; i < 16; i++) d += Ur[i] * X[i];
      cn[jj] = cin[jj] + sc * d;
      if (!last) Cout[(size_t)b * 64 * NN + (size_t)(jw + jj) * NN + m] = cn[jj];
    }
    float lg[32];
    #pragma unroll
    for (int k = 0; k < 32; k++) lg[k] = 0.f;
    #pragma unroll
    for (int jj = 0; jj < 8; jj++) {
      const float* Er = emb + (jw + jj) * 32;
      #pragma unroll
      for (int k = 0; k < 32; k++) lg[k] = fmaf(Er[k], cn[jj], lg[k]);
    }
    #pragma unroll
    for (int k = 0; k < 32; k++) atomicAdd(&Lg[c * 33 + k], lg[k]);
  }

  // prefetch B rows (issue before the barrier; consumed after softmax)
  f4 bc0, bc1, bg0, bg1;
  if (!last) {
    const f4* BC = reinterpret_cast<const f4*>(Bin + ((size_t)b * NN + m) * 64 + jw);
    const f4* BG = reinterpret_cast<const f4*>(Bin + ((size_t)b * NN + nst) * 64 + jw);
    bc0 = BC[0]; bc1 = BC[1];
    bg0 = BG[0]; bg1 = BG[1];
  }
  __syncthreads();

  // ---- softmax (lane-local, redundant across the 8 waves) ----
  float p[32];
  #pragma unroll
  for (int k = 0; k < 32; k++) p[k] = Lg[c * 33 + k];
  float mx = p[0];
  #pragma unroll
  for (int k = 1; k < 32; k++) mx = fmaxf(mx, p[k]);
  float ss = 0.f;
  #pragma unroll
  for (int k = 0; k < 32; k++) { p[k] = __expf(p[k] - mx); ss += p[k]; }
  float inv = 1.0f / ss;
  #pragma unroll
  for (int k = 0; k < 32; k++) p[k] *= inv;

  if (last) {
    if (w == 0) {
      float* lo = out + ((size_t)b * NN + m) * 32;
      float* po = lo + (size_t)NB * NN * 32;
      #pragma unroll
      for (int q = 0; q < 8; q++) {
        f4 vl = {Lg[c*33 + 4*q], Lg[c*33 + 4*q+1], Lg[c*33 + 4*q+2], Lg[c*33 + 4*q+3]};
        f4 vp = {p[4*q], p[4*q+1], p[4*q+2], p[4*q+3]};
        *reinterpret_cast<f4*>(lo + 4*q) = vl;
        *reinterpret_cast<f4*>(po + 4*q) = vp;
      }
    }
    return;
  }

  // ---- B update (rows jw..jw+7 of column m), inputs already in regs ----
  {
    f4* BO = reinterpret_cast<f4*>(Bout + ((size_t)b * NN + m) * 64 + jw);
    const float invM = 1.0f / 1008.0f;
    bool live = (m < 1008);
    #pragma unroll
    for (int jq = 0; jq < 2; jq++) {
      f4 bc = jq ? bc1 : bc0;
      f4 bg = jq ? bg1 : bg0;
      f4 vo;
      #pragma unroll
      for (int kk = 0; kk < 4; kk++) {
        int j = jw + jq * 4 + kk;
        const float* Er = emb + j * 32;
        float v = fmaf(bg[kk], -invM, bc[kk]);
        #pragma unroll
        for (int k = 0; k < 32; k++) v = fmaf(Er[k], p[k], v);
        vo[kk] = v;
        Ws[j * 68 + c] = live ? v : 0.f;
      }
      BO[jq] = vo;
    }
  }
  __syncthreads();

  // ---- Up chunk = w @ X^T via MFMA (waves 0-3) ----
  if (w < 4) {
    int jw16 = w * 16;
    int r = lane & 15, q = lane >> 4;
    f4 acc = {0.f, 0.f, 0.f, 0.f};
    #pragma unroll
    for (int ks = 0; ks < 2; ks++) {
      s8 af = frag8(&Ws[(jw16 + r) * 68 + ks * 32 + q * 8]);
      s8 bf = frag8(&Xf[r * 68 + ks * 32 + q * 8]);
      acc = __builtin_amdgcn_mfma_f32_16x16x32_bf16(af, bf, acc, 0, 0, 0);
    }
    float* upb = Upout + ((size_t)(b * 16 + mt)) * 1024;
    #pragma unroll
    for (int reg = 0; reg < 4; reg++)
      upb[(jw16 + q * 4 + reg) * 16 + r] = acc[reg];
  }
}

extern "C" void kernel_launch(void* const* d_in, const int* in_sizes, int n_in,
                              void* d_out, int out_size, void* d_ws, size_t ws_size,
                              hipStream_t stream)
{
  const float* x     = (const float*)d_in[0];
  const float* alpha = (const float*)d_in[1];
  const float* kp    = (const float*)d_in[2];
  const float* emb   = (const float*)d_in[3];
  float* ws = (float*)d_ws;
  float* B0  = ws + OFF_B0;
  float* B1  = ws + OFF_B1;
  float* C   = ws + OFF_C;
  float* UpA = ws + OFF_UPA;
  float* UpB = ws + OFF_UPB;
  float* UpC = ws + OFF_UPC;
  float* Uc  = ws + OFF_UC;
  int*   ns  = (int*)(ws + OFF_NS);
  float* out = (float*)d_out;

  k_init<<<1536, 256, 0, stream>>>(x, emb, B0, UpC, UpA, ns);
  // layer 0: Cin = x[80:144], B0->B1, UpA (32 chunks) -> UpB (16)
  k_comb<<<128, 256, 0, stream>>>(UpC, UpA, 32, alpha, 0, Uc);
  k_update<<<512, 512, 0, stream>>>(x, emb, kp, Uc, ns,
                                    x + 80 * NN, (size_t)DINR * NN, C,
                                    B0, B1, UpB, 0, out);
  // layer 1: B1->B0, UpB (16) -> UpA (16)
  k_comb<<<128, 256, 0, stream>>>(UpC, UpB, 16, alpha, 1, Uc);
  k_update<<<512, 512, 0, stream>>>(x, emb, kp, Uc, ns,
                                    C, (size_t)64 * NN, C,
                                    B1, B0, UpA, 0, out);
  // layer 2 (last): outputs only
  k_comb<<<128, 256, 0, stream>>>(UpC, UpA, 16, alpha, 2, Uc);
  k_update<<<512, 512, 0, stream>>>(x, emb, kp, Uc, ns,
                                    C, (size_t)64 * NN, C,
                                    B0, B1, UpB, 1, out);
}

// Round 10
// 163.173 us; speedup vs baseline: 1.3096x; 1.3096x over previous
//
#include <hip/hip_runtime.h>
#include <hip/hip_bf16.h>

#define NB 32
#define NN 1024
#define DINR 144

typedef __attribute__((ext_vector_type(4))) float f4;
typedef __attribute__((ext_vector_type(8))) short s8;

// ws float offsets
#define OFF_B0  (0u)
#define OFF_B1  (1u*NB*64*NN)
#define OFF_C   (2u*NB*64*NN)
#define OFF_UPA (3u*NB*64*NN)                 // k_update Up chunks (ping) 4MB
#define OFF_UPB (OFF_UPA + NB*32*1024u)       // (pong) 4MB
#define OFF_GP  (OFF_UPB + NB*32*1024u)       // Gram partials [b][ct][2][512] 4MB
#define OFF_UC  (OFF_GP + NB*32*1024u)        // combined U (per layer)
#define OFF_NS  (OFF_UC + NB*1024u)

static __device__ __forceinline__ unsigned short bf16u(float f) {
  __hip_bfloat16 h = __float2bfloat16(f);
  return *reinterpret_cast<unsigned short*>(&h);
}

// ---------------------------------------------------------------------------
// k_init
//  blocks [0,1024): b=blk>>5, ct=blk&31 (32-col slab):
//    stage x rows 0..79; B0 = E@x3 via MFMA (col-major write);
//    Gram partials G2=x2@X^T, G3=x3@X^T (masked n<1008) -> Gp
//  blocks [1024,1536): nstar = argmax_{n<1008} X[:,m]·X[:,n]  (bf16 MFMA)
// ---------------------------------------------------------------------------
__global__ __launch_bounds__(256) void k_init(
    const float* __restrict__ x, const float* __restrict__ emb,
    float* __restrict__ Bt, float* __restrict__ Gp, int* __restrict__ nstar)
{
  __shared__ union {
    unsigned int XT[NN * 8];                 // 32768 B (argmax part)
    struct {
      float xs[80 * 36];                     // 11520 B (16B-aligned rows)
      unsigned int Eb[64 * 16];              // E rows as bf16 pairs, 4096 B
    } d;
  } sm;
  int t = threadIdx.x;
  if (blockIdx.x < 1024) {
    int b = blockIdx.x >> 5;
    int ct = blockIdx.x & 31;
    int n0 = ct * 32;
    const float* xb = x + (size_t)b * DINR * NN;
    for (int idx = t; idx < 80 * 32; idx += 256) {
      int row = idx >> 5, col = idx & 31;
      sm.d.xs[row * 36 + col] = xb[row * NN + n0 + col];
    }
    for (int e = t; e < 1024; e += 256) {
      int j = e >> 4, hp = e & 15;
      float f0 = emb[j * 32 + hp * 2];
      float f1 = emb[j * 32 + hp * 2 + 1];
      sm.d.Eb[j * 16 + hp] =
          (unsigned int)bf16u(f0) | ((unsigned int)bf16u(f1) << 16);
    }
    __syncthreads();
    // B0 = E @ x3 via MFMA: wave w = j-tile of 16; nt = n-half of 16
    {
      int lane = t & 63, w = t >> 6;
      int r = lane & 15, q = lane >> 4;
      s8 af = *reinterpret_cast<const s8*>(&sm.d.Eb[(w * 16 + r) * 16 + q * 4]);
      #pragma unroll
      for (int nt = 0; nt < 2; nt++) {
        union { s8 v; unsigned short u[8]; } B;
        #pragma unroll
        for (int e = 0; e < 8; e++)
          B.u[e] = bf16u(sm.d.xs[(48 + q * 8 + e) * 36 + nt * 16 + r]);
        f4 acc = {0.f, 0.f, 0.f, 0.f};
        acc = __builtin_amdgcn_mfma_f32_16x16x32_bf16(af, B.v, acc, 0, 0, 0);
        int n = n0 + nt * 16 + r;
        f4* dst = reinterpret_cast<f4*>(
            Bt + ((size_t)b * NN + n) * 64 + w * 16 + q * 4);
        *dst = acc;
      }
    }
    __syncthreads();
    // mask dead columns (only slab containing n>=1008): zero all 80 rows
    if (n0 + 32 > 1008) {
      for (int idx = t; idx < 80 * 16; idx += 256) {
        int row = idx >> 4, col = 16 + (idx & 15);
        sm.d.xs[row * 36 + col] = 0.f;
      }
    }
    __syncthreads();
    // Gram partials: 1024 entries (mat,r,i), 4 per thread
    float* gp = Gp + ((size_t)(b * 32 + ct)) * 1024;
    for (int e = t; e < 1024; e += 256) {
      int mat = e >> 9, r = (e >> 4) & 31, i = e & 15;
      const f4* xr = reinterpret_cast<const f4*>(&sm.d.xs[(16 + mat * 32 + r) * 36]);
      const f4* xi = reinterpret_cast<const f4*>(&sm.d.xs[i * 36]);
      float s = 0.f;
      #pragma unroll
      for (int cq = 0; cq < 8; cq++) {
        f4 a = xr[cq], bq = xi[cq];
        s += a[0]*bq[0] + a[1]*bq[1] + a[2]*bq[2] + a[3]*bq[3];
      }
      gp[e] = s;
    }
  } else {
    int a = blockIdx.x - 1024;
    int b = a >> 4;
    int mg = a & 15;
    const float* xb = x + (size_t)b * DINR * NN;
    #pragma unroll
    for (int rep = 0; rep < 4; rep++) {
      int n = t + (rep << 8);
      unsigned int pk[8];
      #pragma unroll
      for (int h = 0; h < 8; h++) {
        unsigned int u0 = __float_as_uint(xb[(2*h) * NN + n]);
        unsigned int u1 = __float_as_uint(xb[(2*h+1) * NN + n]);
        pk[h] = (u0 >> 16) | (u1 & 0xFFFF0000u);
      }
      #pragma unroll
      for (int h = 0; h < 8; h++) sm.XT[n * 8 + h] = pk[h];
    }
    __syncthreads();
    int w = t >> 6;
    int lane = t & 63;
    int r = lane & 15;
    int g = lane >> 4;
    int mt = mg * 64 + w * 16;
    s8 zero8 = {0,0,0,0,0,0,0,0};
    s8 afrag = zero8;
    if (g < 2) afrag = *reinterpret_cast<const s8*>(&sm.XT[(mt + r) * 8 + g * 4]);
    float bestv[4];
    int besti[4];
    #pragma unroll
    for (int j = 0; j < 4; j++) { bestv[j] = -3.4e38f; besti[j] = 0x7FFFFFFF; }
    for (int nt = 0; nt < 63; nt++) {
      s8 bfrag = zero8;
      if (g < 2) bfrag = *reinterpret_cast<const s8*>(&sm.XT[(nt*16 + r) * 8 + g * 4]);
      f4 acc = {0.f, 0.f, 0.f, 0.f};
      acc = __builtin_amdgcn_mfma_f32_16x16x32_bf16(afrag, bfrag, acc, 0, 0, 0);
      int n = nt * 16 + r;
      #pragma unroll
      for (int j = 0; j < 4; j++) {
        float v = acc[j];
        bool better = (v > bestv[j]) || (v == bestv[j] && n < besti[j]);
        if (better) { bestv[j] = v; besti[j] = n; }
      }
    }
    #pragma unroll
    for (int s = 1; s < 16; s <<= 1) {
      #pragma unroll
      for (int j = 0; j < 4; j++) {
        float ov = __shfl_xor(bestv[j], s, 64);
        int   oi = __shfl_xor(besti[j], s, 64);
        bool better = (ov > bestv[j]) || (ov == bestv[j] && oi < besti[j]);
        if (better) { bestv[j] = ov; besti[j] = oi; }
      }
    }
    if (r == 0) {
      #pragma unroll
      for (int j = 0; j < 4; j++)
        nstar[b * NN + mt + g * 4 + j] = besti[j];
    }
  }
}

// ---------------------------------------------------------------------------
// k_comb: Uc[j][i] = alpha_l[j] * ( E[j][:]·G[:,i] − SB[j][i] )
//   G = ΣctG2 (l>0) or Σct(G2−G3) (l==0);  SB = Σch UpB chunks (l>0) else 0
// grid 128 = 32 b x 4 quarters, 256 threads
// ---------------------------------------------------------------------------
__global__ __launch_bounds__(256) void k_comb(
    const float* __restrict__ Gp, const float* __restrict__ UpB, int useUp,
    const float* __restrict__ emb, const float* __restrict__ alpha, int l,
    float* __restrict__ Uc)
{
  __shared__ float G[512];
  int b = blockIdx.x >> 2;
  int qd = blockIdx.x & 3;
  int t = threadIdx.x;
  for (int e = t; e < 512; e += 256) {
    const float* p2 = Gp + (size_t)b * 32 * 1024 + e;
    float s = 0.f;
    #pragma unroll 8
    for (int ct = 0; ct < 32; ct++) s += p2[ct * 1024];
    if (!useUp) {
      const float* p3 = p2 + 512;
      float s3 = 0.f;
      #pragma unroll 8
      for (int ct = 0; ct < 32; ct++) s3 += p3[ct * 1024];
      s -= s3;
    }
    G[e] = s;
  }
  __syncthreads();
  int e = qd * 256 + t;
  int j = e >> 4, i = e & 15;
  const float* Er = emb + j * 32;
  float acc = 0.f;
  #pragma unroll
  for (int r = 0; r < 32; r++) acc = fmaf(Er[r], G[r * 16 + i], acc);
  float sb = 0.f;
  if (useUp) {
    const float* pb = UpB + (size_t)b * 32 * 1024 + e;
    #pragma unroll 8
    for (int ch = 0; ch < 32; ch++) sb += pb[ch * 1024];
  }
  Uc[(size_t)b * 1024 + e] = alpha[l * 64 + j] * (acc - sb);
}

// ---------------------------------------------------------------------------
// k_update (R5-proven, unchanged): C'=C+sc*U@X; logits=E^T C'; p=softmax;
//   if !last: Bout = B - B[nstar]/M + Ep ; Up_next chunk (LDS dot)
// grid 1024 = 32 b x 32 m-tiles of 32 cols; c=t>>3 (col), g=t&7 (j-octet)
// ---------------------------------------------------------------------------
__global__ __launch_bounds__(256) void k_update(
    const float* __restrict__ x, const float* __restrict__ emb,
    const float* __restrict__ kpp, const float* __restrict__ Uc,
    const int* __restrict__ nstar,
    const float* __restrict__ Cin, size_t cbs, float* __restrict__ Cout,
    const float* __restrict__ Bin, float* __restrict__ Bout,
    float* __restrict__ Upout, int last, float* __restrict__ out)
{
  __shared__ float Us[1024];       // swizzled combined U
  __shared__ float Ess[2048];      // E as f4[512], swizzled
  __shared__ float Xs[16 * 33];
  __shared__ float Cs[64 * 33];    // C' tile; reused for w after writeback
  int t = threadIdx.x;
  int b = blockIdx.x >> 5;
  int mt = blockIdx.x & 31;
  int n0 = mt * 32;
  for (int idx = t; idx < 1024; idx += 256) {
    float s = Uc[(size_t)b * 1024 + idx];
    int j = idx >> 4, i = idx & 15;
    Us[j * 16 + ((((i >> 2) ^ (j >> 3)) & 3) << 2) + (i & 3)] = s;
  }
  f4* es4 = reinterpret_cast<f4*>(Ess);
  const f4* E4g = reinterpret_cast<const f4*>(emb);
  for (int fj = t; fj < 512; fj += 256) {
    int j = fj >> 3, cc = fj & 7;
    es4[j * 8 + ((cc ^ (j >> 3)) & 7)] = E4g[fj];
  }
  const float* xb = x + (size_t)b * DINR * NN;
  for (int idx = t; idx < 512; idx += 256) {
    int r = idx >> 5, cl = idx & 31;
    Xs[r * 33 + cl] = xb[r * NN + n0 + cl];
  }
  for (int idx = t; idx < 2048; idx += 256) {
    int r = idx >> 5, cl = idx & 31;
    Cs[r * 33 + cl] = Cin[(size_t)b * cbs + r * NN + n0 + cl];
  }
  __syncthreads();
  int c = t >> 3, g = t & 7;
  int m = n0 + c;
  float X[16];
  #pragma unroll
  for (int i = 0; i < 16; i++) X[i] = Xs[i * 33 + c];
  float sc = kpp[0] * (1.0f / 1008.0f);
  float lg[32];
  #pragma unroll
  for (int k = 0; k < 32; k++) lg[k] = 0.f;
  const f4* U4 = reinterpret_cast<const f4*>(Us);
  #pragma unroll
  for (int jj = 0; jj < 8; jj++) {
    int j = g * 8 + jj;
    float d = 0.f;
    #pragma unroll
    for (int ii = 0; ii < 4; ii++) {
      f4 u = U4[j * 4 + ((ii ^ g) & 3)];
      d += u[0]*X[4*ii] + u[1]*X[4*ii+1] + u[2]*X[4*ii+2] + u[3]*X[4*ii+3];
    }
    float cn = Cs[j * 33 + c] + sc * d;
    Cs[j * 33 + c] = cn;          // unique owner per (j,c) slot
    #pragma unroll
    for (int cc = 0; cc < 8; cc++) {
      f4 e = es4[j * 8 + ((cc ^ g) & 7)];
      lg[4*cc+0] += cn * e[0]; lg[4*cc+1] += cn * e[1];
      lg[4*cc+2] += cn * e[2]; lg[4*cc+3] += cn * e[3];
    }
  }
  if (!last) {
    __syncthreads();
    float* Cb = Cout + (size_t)b * 64 * NN;
    for (int idx = t; idx < 2048; idx += 256) {
      int r = idx >> 5, cl = idx & 31;
      Cb[r * NN + n0 + cl] = Cs[r * 33 + cl];
    }
    __syncthreads();   // Cs free for reuse after this point
  }
  #pragma unroll
  for (int s = 1; s < 8; s <<= 1) {
    #pragma unroll
    for (int k = 0; k < 32; k++) lg[k] += __shfl_xor(lg[k], s, 64);
  }
  #define QUAD(gg) (f4){lg[4*(gg)], lg[4*(gg)+1], lg[4*(gg)+2], lg[4*(gg)+3]}
  f4 vlog;
  if (last) {
    switch (g) {
      case 0: vlog = QUAD(0); break;  case 1: vlog = QUAD(1); break;
      case 2: vlog = QUAD(2); break;  case 3: vlog = QUAD(3); break;
      case 4: vlog = QUAD(4); break;  case 5: vlog = QUAD(5); break;
      case 6: vlog = QUAD(6); break;  default: vlog = QUAD(7); break;
    }
  }
  float mx = lg[0];
  #pragma unroll
  for (int k = 1; k < 32; k++) mx = fmaxf(mx, lg[k]);
  float ssum = 0.f;
  #pragma unroll
  for (int k = 0; k < 32; k++) { lg[k] = __expf(lg[k] - mx); ssum += lg[k]; }
  float inv = 1.0f / ssum;
  #pragma unroll
  for (int k = 0; k < 32; k++) lg[k] *= inv;
  if (last) {
    f4 vpred;
    switch (g) {
      case 0: vpred = QUAD(0); break;  case 1: vpred = QUAD(1); break;
      case 2: vpred = QUAD(2); break;  case 3: vpred = QUAD(3); break;
      case 4: vpred = QUAD(4); break;  case 5: vpred = QUAD(5); break;
      case 6: vpred = QUAD(6); break;  default: vpred = QUAD(7); break;
    }
    float* lo = out + ((size_t)b * NN + m) * 32 + g * 4;
    float* po = lo + (size_t)NB * NN * 32;
    *reinterpret_cast<f4*>(lo) = vlog;
    *reinterpret_cast<f4*>(po) = vpred;
    return;
  }
  #undef QUAD
  // B update rows g*8..g*8+7 of column m
  int nst = nstar[b * NN + m];
  const f4* BC = reinterpret_cast<const f4*>(Bin + ((size_t)b * NN + m) * 64 + g * 8);
  const f4* BG = reinterpret_cast<const f4*>(Bin + ((size_t)b * NN + nst) * 64 + g * 8);
  f4* BO = reinterpret_cast<f4*>(Bout + ((size_t)b * NN + m) * 64 + g * 8);
  const float invM = 1.0f / 1008.0f;
  bool live = (m < 1008);
  float vv[8];
  #pragma unroll
  for (int jg = 0; jg < 2; jg++) {
    f4 bc4 = BC[jg];
    f4 bg4 = BG[jg];
    f4 vo;
    #pragma unroll
    for (int k = 0; k < 4; k++) {
      int j = g * 8 + jg * 4 + k;
      float v = bc4[k] - bg4[k] * invM;
      #pragma unroll
      for (int cc = 0; cc < 8; cc++) {
        f4 e = es4[j * 8 + ((cc ^ g) & 7)];
        v += e[0]*lg[4*cc] + e[1]*lg[4*cc+1] + e[2]*lg[4*cc+2] + e[3]*lg[4*cc+3];
      }
      vo[k] = v;
      vv[jg * 4 + k] = v;
    }
    BO[jg] = vo;
  }
  #pragma unroll
  for (int jj = 0; jj < 8; jj++)
    Cs[(g * 8 + jj) * 33 + c] = live ? vv[jj] : 0.f;
  __syncthreads();
  float* upb = Upout + ((size_t)(b * 32 + mt)) * 1024;
  for (int idx = t; idx < 1024; idx += 256) {
    int j = idx >> 4, i = idx & 15;
    float s = 0.f;
    #pragma unroll
    for (int cc = 0; cc < 32; cc++) s += Cs[j * 33 + cc] * Xs[i * 33 + cc];
    upb[idx] = s;
  }
}

extern "C" void kernel_launch(void* const* d_in, const int* in_sizes, int n_in,
                              void* d_out, int out_size, void* d_ws, size_t ws_size,
                              hipStream_t stream)
{
  const float* x     = (const float*)d_in[0];
  const float* alpha = (const float*)d_in[1];
  const float* kp    = (const float*)d_in[2];
  const float* emb   = (const float*)d_in[3];
  float* ws = (float*)d_ws;
  float* B0  = ws + OFF_B0;
  float* B1  = ws + OFF_B1;
  float* C   = ws + OFF_C;
  float* UpA = ws + OFF_UPA;
  float* UpB = ws + OFF_UPB;
  float* Gp  = ws + OFF_GP;
  float* Uc  = ws + OFF_UC;
  int*   ns  = (int*)(ws + OFF_NS);
  float* out = (float*)d_out;

  k_init<<<1536, 256, 0, stream>>>(x, emb, B0, Gp, ns);
  // layer 0: Uc = alpha(E@(G2-G3)); Cin = x[80:144]; B0->B1; Up chunks -> UpA
  k_comb<<<128, 256, 0, stream>>>(Gp, UpA, 0, emb, alpha, 0, Uc);
  k_update<<<1024, 256, 0, stream>>>(x, emb, kp, Uc, ns,
                                     x + 80 * NN, (size_t)DINR * NN, C,
                                     B0, B1, UpA, 0, out);
  // layer 1: Uc = alpha(E@G2 - sum UpA); B1->B0; -> UpB
  k_comb<<<128, 256, 0, stream>>>(Gp, UpA, 1, emb, alpha, 1, Uc);
  k_update<<<1024, 256, 0, stream>>>(x, emb, kp, Uc, ns,
                                     C, (size_t)64 * NN, C,
                                     B1, B0, UpB, 0, out);
  // layer 2 (last): Uc = alpha(E@G2 - sum UpB); outputs only
  k_comb<<<128, 256, 0, stream>>>(Gp, UpB, 1, emb, alpha, 2, Uc);
  k_update<<<1024, 256, 0, stream>>>(x, emb, kp, Uc, ns,
                                     C, (size_t)64 * NN, C,
                                     B0, B1, UpA, 1, out);
}

// Round 11
// 156.022 us; speedup vs baseline: 1.3696x; 1.0458x over previous
//
#include <hip/hip_runtime.h>
#include <hip/hip_bf16.h>

#define NB 32
#define NN 1024
#define DINR 144

typedef __attribute__((ext_vector_type(4))) float f4;
typedef __attribute__((ext_vector_type(8))) short s8;

// ws float offsets
#define OFF_B0  (0u)
#define OFF_B1  (1u*NB*64*NN)
#define OFF_C   (2u*NB*64*NN)
#define OFF_UPA (3u*NB*64*NN)                 // k_update Up chunks (ping) 4MB
#define OFF_UPB (OFF_UPA + NB*32*1024u)       // (pong) 4MB
#define OFF_GP  (OFF_UPB + NB*32*1024u)       // Gram partials [b][ct][2][512] 4MB
#define OFF_UC  (OFF_GP + NB*32*1024u)        // combined U (per layer)
#define OFF_NS  (OFF_UC + NB*1024u)

static __device__ __forceinline__ unsigned short bf16u(float f) {
  __hip_bfloat16 h = __float2bfloat16(f);
  return *reinterpret_cast<unsigned short*>(&h);
}

// ---------------------------------------------------------------------------
// k_init  (unchanged from R10)
//  blocks [0,1024): B0 = E@x3 via MFMA (col-major); Gram partials G2,G3 -> Gp
//  blocks [1024,1536): nstar = argmax_{n<1008} X[:,m]·X[:,n]  (bf16 MFMA)
// ---------------------------------------------------------------------------
__global__ __launch_bounds__(256) void k_init(
    const float* __restrict__ x, const float* __restrict__ emb,
    float* __restrict__ Bt, float* __restrict__ Gp, int* __restrict__ nstar)
{
  __shared__ union {
    unsigned int XT[NN * 8];                 // 32768 B (argmax part)
    struct {
      float xs[80 * 36];                     // 11520 B (16B-aligned rows)
      unsigned int Eb[64 * 16];              // E rows as bf16 pairs, 4096 B
    } d;
  } sm;
  int t = threadIdx.x;
  if (blockIdx.x < 1024) {
    int b = blockIdx.x >> 5;
    int ct = blockIdx.x & 31;
    int n0 = ct * 32;
    const float* xb = x + (size_t)b * DINR * NN;
    for (int idx = t; idx < 80 * 32; idx += 256) {
      int row = idx >> 5, col = idx & 31;
      sm.d.xs[row * 36 + col] = xb[row * NN + n0 + col];
    }
    for (int e = t; e < 1024; e += 256) {
      int j = e >> 4, hp = e & 15;
      float f0 = emb[j * 32 + hp * 2];
      float f1 = emb[j * 32 + hp * 2 + 1];
      sm.d.Eb[j * 16 + hp] =
          (unsigned int)bf16u(f0) | ((unsigned int)bf16u(f1) << 16);
    }
    __syncthreads();
    // B0 = E @ x3 via MFMA: wave w = j-tile of 16; nt = n-half of 16
    {
      int lane = t & 63, w = t >> 6;
      int r = lane & 15, q = lane >> 4;
      s8 af = *reinterpret_cast<const s8*>(&sm.d.Eb[(w * 16 + r) * 16 + q * 4]);
      #pragma unroll
      for (int nt = 0; nt < 2; nt++) {
        union { s8 v; unsigned short u[8]; } B;
        #pragma unroll
        for (int e = 0; e < 8; e++)
          B.u[e] = bf16u(sm.d.xs[(48 + q * 8 + e) * 36 + nt * 16 + r]);
        f4 acc = {0.f, 0.f, 0.f, 0.f};
        acc = __builtin_amdgcn_mfma_f32_16x16x32_bf16(af, B.v, acc, 0, 0, 0);
        int n = n0 + nt * 16 + r;
        f4* dst = reinterpret_cast<f4*>(
            Bt + ((size_t)b * NN + n) * 64 + w * 16 + q * 4);
        *dst = acc;
      }
    }
    __syncthreads();
    // mask dead columns (only slab containing n>=1008): zero all 80 rows
    if (n0 + 32 > 1008) {
      for (int idx = t; idx < 80 * 16; idx += 256) {
        int row = idx >> 4, col = 16 + (idx & 15);
        sm.d.xs[row * 36 + col] = 0.f;
      }
    }
    __syncthreads();
    // Gram partials: 1024 entries (mat,r,i), 4 per thread
    float* gp = Gp + ((size_t)(b * 32 + ct)) * 1024;
    for (int e = t; e < 1024; e += 256) {
      int mat = e >> 9, r = (e >> 4) & 31, i = e & 15;
      const f4* xr = reinterpret_cast<const f4*>(&sm.d.xs[(16 + mat * 32 + r) * 36]);
      const f4* xi = reinterpret_cast<const f4*>(&sm.d.xs[i * 36]);
      float s = 0.f;
      #pragma unroll
      for (int cq = 0; cq < 8; cq++) {
        f4 a = xr[cq], bq = xi[cq];
        s += a[0]*bq[0] + a[1]*bq[1] + a[2]*bq[2] + a[3]*bq[3];
      }
      gp[e] = s;
    }
  } else {
    int a = blockIdx.x - 1024;
    int b = a >> 4;
    int mg = a & 15;
    const float* xb = x + (size_t)b * DINR * NN;
    #pragma unroll
    for (int rep = 0; rep < 4; rep++) {
      int n = t + (rep << 8);
      unsigned int pk[8];
      #pragma unroll
      for (int h = 0; h < 8; h++) {
        unsigned int u0 = __float_as_uint(xb[(2*h) * NN + n]);
        unsigned int u1 = __float_as_uint(xb[(2*h+1) * NN + n]);
        pk[h] = (u0 >> 16) | (u1 & 0xFFFF0000u);
      }
      #pragma unroll
      for (int h = 0; h < 8; h++) sm.XT[n * 8 + h] = pk[h];
    }
    __syncthreads();
    int w = t >> 6;
    int lane = t & 63;
    int r = lane & 15;
    int g = lane >> 4;
    int mt = mg * 64 + w * 16;
    s8 zero8 = {0,0,0,0,0,0,0,0};
    s8 afrag = zero8;
    if (g < 2) afrag = *reinterpret_cast<const s8*>(&sm.XT[(mt + r) * 8 + g * 4]);
    float bestv[4];
    int besti[4];
    #pragma unroll
    for (int j = 0; j < 4; j++) { bestv[j] = -3.4e38f; besti[j] = 0x7FFFFFFF; }
    for (int nt = 0; nt < 63; nt++) {
      s8 bfrag = zero8;
      if (g < 2) bfrag = *reinterpret_cast<const s8*>(&sm.XT[(nt*16 + r) * 8 + g * 4]);
      f4 acc = {0.f, 0.f, 0.f, 0.f};
      acc = __builtin_amdgcn_mfma_f32_16x16x32_bf16(afrag, bfrag, acc, 0, 0, 0);
      int n = nt * 16 + r;
      #pragma unroll
      for (int j = 0; j < 4; j++) {
        float v = acc[j];
        bool better = (v > bestv[j]) || (v == bestv[j] && n < besti[j]);
        if (better) { bestv[j] = v; besti[j] = n; }
      }
    }
    #pragma unroll
    for (int s = 1; s < 16; s <<= 1) {
      #pragma unroll
      for (int j = 0; j < 4; j++) {
        float ov = __shfl_xor(bestv[j], s, 64);
        int   oi = __shfl_xor(besti[j], s, 64);
        bool better = (ov > bestv[j]) || (ov == bestv[j] && oi < besti[j]);
        if (better) { bestv[j] = ov; besti[j] = oi; }
      }
    }
    if (r == 0) {
      #pragma unroll
      for (int j = 0; j < 4; j++)
        nstar[b * NN + mt + g * 4 + j] = besti[j];
    }
  }
}

// ---------------------------------------------------------------------------
// k_comb: Uc[j][i] = alpha_l[j] * ( E[j][:]·G[:,i] − SB[j][i] )   (unchanged)
// ---------------------------------------------------------------------------
__global__ __launch_bounds__(256) void k_comb(
    const float* __restrict__ Gp, const float* __restrict__ UpB, int useUp,
    const float* __restrict__ emb, const float* __restrict__ alpha, int l,
    float* __restrict__ Uc)
{
  __shared__ float G[512];
  int b = blockIdx.x >> 2;
  int qd = blockIdx.x & 3;
  int t = threadIdx.x;
  for (int e = t; e < 512; e += 256) {
    const float* p2 = Gp + (size_t)b * 32 * 1024 + e;
    float s = 0.f;
    #pragma unroll 8
    for (int ct = 0; ct < 32; ct++) s += p2[ct * 1024];
    if (!useUp) {
      const float* p3 = p2 + 512;
      float s3 = 0.f;
      #pragma unroll 8
      for (int ct = 0; ct < 32; ct++) s3 += p3[ct * 1024];
      s -= s3;
    }
    G[e] = s;
  }
  __syncthreads();
  int e = qd * 256 + t;
  int j = e >> 4, i = e & 15;
  const float* Er = emb + j * 32;
  float acc = 0.f;
  #pragma unroll
  for (int r = 0; r < 32; r++) acc = fmaf(Er[r], G[r * 16 + i], acc);
  float sb = 0.f;
  if (useUp) {
    const float* pb = UpB + (size_t)b * 32 * 1024 + e;
    #pragma unroll 8
    for (int ch = 0; ch < 32; ch++) sb += pb[ch * 1024];
  }
  Uc[(size_t)b * 1024 + e] = alpha[l * 64 + j] * (acc - sb);
}

// ---------------------------------------------------------------------------
// k_update: R10-proven body; ONLY the Up-chunk tail replaced by MFMA.
// grid 1024 = 32 b x 32 m-tiles of 32 cols; c=t>>3 (col), g=t&7 (j-octet)
// ---------------------------------------------------------------------------
__global__ __launch_bounds__(256) void k_update(
    const float* __restrict__ x, const float* __restrict__ emb,
    const float* __restrict__ kpp, const float* __restrict__ Uc,
    const int* __restrict__ nstar,
    const float* __restrict__ Cin, size_t cbs, float* __restrict__ Cout,
    const float* __restrict__ Bin, float* __restrict__ Bout,
    float* __restrict__ Upout, int last, float* __restrict__ out)
{
  __shared__ float Us[1024];       // swizzled combined U
  __shared__ float Ess[2048];      // E as f4[512], swizzled
  __shared__ float Xs[16 * 33];
  __shared__ float Cs[64 * 33];    // C' tile; reused for w after writeback
  int t = threadIdx.x;
  int b = blockIdx.x >> 5;
  int mt = blockIdx.x & 31;
  int n0 = mt * 32;
  for (int idx = t; idx < 1024; idx += 256) {
    float s = Uc[(size_t)b * 1024 + idx];
    int j = idx >> 4, i = idx & 15;
    Us[j * 16 + ((((i >> 2) ^ (j >> 3)) & 3) << 2) + (i & 3)] = s;
  }
  f4* es4 = reinterpret_cast<f4*>(Ess);
  const f4* E4g = reinterpret_cast<const f4*>(emb);
  for (int fj = t; fj < 512; fj += 256) {
    int j = fj >> 3, cc = fj & 7;
    es4[j * 8 + ((cc ^ (j >> 3)) & 7)] = E4g[fj];
  }
  const float* xb = x + (size_t)b * DINR * NN;
  for (int idx = t; idx < 512; idx += 256) {
    int r = idx >> 5, cl = idx & 31;
    Xs[r * 33 + cl] = xb[r * NN + n0 + cl];
  }
  for (int idx = t; idx < 2048; idx += 256) {
    int r = idx >> 5, cl = idx & 31;
    Cs[r * 33 + cl] = Cin[(size_t)b * cbs + r * NN + n0 + cl];
  }
  __syncthreads();
  int c = t >> 3, g = t & 7;
  int m = n0 + c;
  float X[16];
  #pragma unroll
  for (int i = 0; i < 16; i++) X[i] = Xs[i * 33 + c];
  float sc = kpp[0] * (1.0f / 1008.0f);
  float lg[32];
  #pragma unroll
  for (int k = 0; k < 32; k++) lg[k] = 0.f;
  const f4* U4 = reinterpret_cast<const f4*>(Us);
  #pragma unroll
  for (int jj = 0; jj < 8; jj++) {
    int j = g * 8 + jj;
    float d = 0.f;
    #pragma unroll
    for (int ii = 0; ii < 4; ii++) {
      f4 u = U4[j * 4 + ((ii ^ g) & 3)];
      d += u[0]*X[4*ii] + u[1]*X[4*ii+1] + u[2]*X[4*ii+2] + u[3]*X[4*ii+3];
    }
    float cn = Cs[j * 33 + c] + sc * d;
    Cs[j * 33 + c] = cn;          // unique owner per (j,c) slot
    #pragma unroll
    for (int cc = 0; cc < 8; cc++) {
      f4 e = es4[j * 8 + ((cc ^ g) & 7)];
      lg[4*cc+0] += cn * e[0]; lg[4*cc+1] += cn * e[1];
      lg[4*cc+2] += cn * e[2]; lg[4*cc+3] += cn * e[3];
    }
  }
  if (!last) {
    __syncthreads();
    float* Cb = Cout + (size_t)b * 64 * NN;
    for (int idx = t; idx < 2048; idx += 256) {
      int r = idx >> 5, cl = idx & 31;
      Cb[r * NN + n0 + cl] = Cs[r * 33 + cl];
    }
    __syncthreads();   // Cs free for reuse after this point
  }
  #pragma unroll
  for (int s = 1; s < 8; s <<= 1) {
    #pragma unroll
    for (int k = 0; k < 32; k++) lg[k] += __shfl_xor(lg[k], s, 64);
  }
  #define QUAD(gg) (f4){lg[4*(gg)], lg[4*(gg)+1], lg[4*(gg)+2], lg[4*(gg)+3]}
  f4 vlog;
  if (last) {
    switch (g) {
      case 0: vlog = QUAD(0); break;  case 1: vlog = QUAD(1); break;
      case 2: vlog = QUAD(2); break;  case 3: vlog = QUAD(3); break;
      case 4: vlog = QUAD(4); break;  case 5: vlog = QUAD(5); break;
      case 6: vlog = QUAD(6); break;  default: vlog = QUAD(7); break;
    }
  }
  float mx = lg[0];
  #pragma unroll
  for (int k = 1; k < 32; k++) mx = fmaxf(mx, lg[k]);
  float ssum = 0.f;
  #pragma unroll
  for (int k = 0; k < 32; k++) { lg[k] = __expf(lg[k] - mx); ssum += lg[k]; }
  float inv = 1.0f / ssum;
  #pragma unroll
  for (int k = 0; k < 32; k++) lg[k] *= inv;
  if (last) {
    f4 vpred;
    switch (g) {
      case 0: vpred = QUAD(0); break;  case 1: vpred = QUAD(1); break;
      case 2: vpred = QUAD(2); break;  case 3: vpred = QUAD(3); break;
      case 4: vpred = QUAD(4); break;  case 5: vpred = QUAD(5); break;
      case 6: vpred = QUAD(6); break;  default: vpred = QUAD(7); break;
    }
    float* lo = out + ((size_t)b * NN + m) * 32 + g * 4;
    float* po = lo + (size_t)NB * NN * 32;
    *reinterpret_cast<f4*>(lo) = vlog;
    *reinterpret_cast<f4*>(po) = vpred;
    return;
  }
  #undef QUAD
  // B update rows g*8..g*8+7 of column m
  int nst = nstar[b * NN + m];
  const f4* BC = reinterpret_cast<const f4*>(Bin + ((size_t)b * NN + m) * 64 + g * 8);
  const f4* BG = reinterpret_cast<const f4*>(Bin + ((size_t)b * NN + nst) * 64 + g * 8);
  f4* BO = reinterpret_cast<f4*>(Bout + ((size_t)b * NN + m) * 64 + g * 8);
  const float invM = 1.0f / 1008.0f;
  bool live = (m < 1008);
  float vv[8];
  #pragma unroll
  for (int jg = 0; jg < 2; jg++) {
    f4 bc4 = BC[jg];
    f4 bg4 = BG[jg];
    f4 vo;
    #pragma unroll
    for (int k = 0; k < 4; k++) {
      int j = g * 8 + jg * 4 + k;
      float v = bc4[k] - bg4[k] * invM;
      #pragma unroll
      for (int cc = 0; cc < 8; cc++) {
        f4 e = es4[j * 8 + ((cc ^ g) & 7)];
        v += e[0]*lg[4*cc] + e[1]*lg[4*cc+1] + e[2]*lg[4*cc+2] + e[3]*lg[4*cc+3];
      }
      vo[k] = v;
      vv[jg * 4 + k] = v;
    }
    BO[jg] = vo;
  }
  #pragma unroll
  for (int jj = 0; jj < 8; jj++)
    Cs[(g * 8 + jj) * 33 + c] = live ? vv[jj] : 0.f;
  __syncthreads();
  // ---- Up chunk = w @ X^T via one MFMA 16x16x32 per wave ----
  {
    int lane = t & 63, wv = t >> 6;
    int r = lane & 15, q = lane >> 4;
    union { s8 v; unsigned short u[8]; } A, Bf;
    #pragma unroll
    for (int e = 0; e < 8; e++)
      A.u[e] = bf16u(Cs[(wv * 16 + r) * 33 + q * 8 + e]);   // w[j=wv*16+r][c=q*8+e]
    #pragma unroll
    for (int e = 0; e < 8; e++)
      Bf.u[e] = bf16u(Xs[r * 33 + q * 8 + e]);              // X[i=r][c=q*8+e]
    f4 acc = {0.f, 0.f, 0.f, 0.f};
    acc = __builtin_amdgcn_mfma_f32_16x16x32_bf16(A.v, Bf.v, acc, 0, 0, 0);
    float* upb = Upout + ((size_t)(b * 32 + mt)) * 1024;
    #pragma unroll
    for (int reg = 0; reg < 4; reg++)
      upb[(wv * 16 + q * 4 + reg) * 16 + r] = acc[reg];
  }
}

extern "C" void kernel_launch(void* const* d_in, const int* in_sizes, int n_in,
                              void* d_out, int out_size, void* d_ws, size_t ws_size,
                              hipStream_t stream)
{
  const float* x     = (const float*)d_in[0];
  const float* alpha = (const float*)d_in[1];
  const float* kp    = (const float*)d_in[2];
  const float* emb   = (const float*)d_in[3];
  float* ws = (float*)d_ws;
  float* B0  = ws + OFF_B0;
  float* B1  = ws + OFF_B1;
  float* C   = ws + OFF_C;
  float* UpA = ws + OFF_UPA;
  float* UpB = ws + OFF_UPB;
  float* Gp  = ws + OFF_GP;
  float* Uc  = ws + OFF_UC;
  int*   ns  = (int*)(ws + OFF_NS);
  float* out = (float*)d_out;

  k_init<<<1536, 256, 0, stream>>>(x, emb, B0, Gp, ns);
  // layer 0: Uc = alpha(E@(G2-G3)); Cin = x[80:144]; B0->B1; Up chunks -> UpA
  k_comb<<<128, 256, 0, stream>>>(Gp, UpA, 0, emb, alpha, 0, Uc);
  k_update<<<1024, 256, 0, stream>>>(x, emb, kp, Uc, ns,
                                     x + 80 * NN, (size_t)DINR * NN, C,
                                     B0, B1, UpA, 0, out);
  // layer 1: Uc = alpha(E@G2 - sum UpA); B1->B0; -> UpB
  k_comb<<<128, 256, 0, stream>>>(Gp, UpA, 1, emb, alpha, 1, Uc);
  k_update<<<1024, 256, 0, stream>>>(x, emb, kp, Uc, ns,
                                     C, (size_t)64 * NN, C,
                                     B1, B0, UpB, 0, out);
  // layer 2 (last): Uc = alpha(E@G2 - sum UpB); outputs only
  k_comb<<<128, 256, 0, stream>>>(Gp, UpB, 1, emb, alpha, 2, Uc);
  k_update<<<1024, 256, 0, stream>>>(x, emb, kp, Uc, ns,
                                     C, (size_t)64 * NN, C,
                                     B0, B1, UpA, 1, out);
}

// Round 15
// 93.150 us; speedup vs baseline: 2.2940x; 1.6750x over previous
//
#include <hip/hip_runtime.h>
#include <hip/hip_bf16.h>

#define NB 32
#define NN 1024
#define DINR 144

typedef __attribute__((ext_vector_type(4))) float f4;
typedef __attribute__((ext_vector_type(8))) short s8;

// ws float offsets
#define OFF_B0  (0u)
#define OFF_B1  (1u*NB*64*NN)
#define OFF_C   (2u*NB*64*NN)
#define OFF_UPA (3u*NB*64*NN)                 // k_update Up chunks (ping)
#define OFF_UPB (OFF_UPA + NB*32*1024u)       // (pong)
#define OFF_GP  (OFF_UPB + NB*32*1024u)       // Gram partials [b][ct][2][512]
#define OFF_UC  (OFF_GP + NB*32*1024u)        // combined U (per layer)
#define OFF_NS  (OFF_UC + NB*1024u)

static __device__ __forceinline__ unsigned short bf16u(float f) {
  __hip_bfloat16 h = __float2bfloat16(f);
  return *reinterpret_cast<unsigned short*>(&h);
}

// ---------------------------------------------------------------------------
// k_init  (unchanged — proven)
// ---------------------------------------------------------------------------
__global__ __launch_bounds__(256) void k_init(
    const float* __restrict__ x, const float* __restrict__ emb,
    float* __restrict__ Bt, float* __restrict__ Gp, int* __restrict__ nstar)
{
  __shared__ union {
    unsigned int XT[NN * 8];
    struct {
      float xs[80 * 36];
      unsigned int Eb[64 * 16];
    } d;
  } sm;
  int t = threadIdx.x;
  if (blockIdx.x < 1024) {
    int b = blockIdx.x >> 5;
    int ct = blockIdx.x & 31;
    int n0 = ct * 32;
    const float* xb = x + (size_t)b * DINR * NN;
    for (int idx = t; idx < 80 * 32; idx += 256) {
      int row = idx >> 5, col = idx & 31;
      sm.d.xs[row * 36 + col] = xb[row * NN + n0 + col];
    }
    for (int e = t; e < 1024; e += 256) {
      int j = e >> 4, hp = e & 15;
      float f0 = emb[j * 32 + hp * 2];
      float f1 = emb[j * 32 + hp * 2 + 1];
      sm.d.Eb[j * 16 + hp] =
          (unsigned int)bf16u(f0) | ((unsigned int)bf16u(f1) << 16);
    }
    __syncthreads();
    {
      int lane = t & 63, w = t >> 6;
      int r = lane & 15, q = lane >> 4;
      s8 af = *reinterpret_cast<const s8*>(&sm.d.Eb[(w * 16 + r) * 16 + q * 4]);
      #pragma unroll
      for (int nt = 0; nt < 2; nt++) {
        union { s8 v; unsigned short u[8]; } B;
        #pragma unroll
        for (int e = 0; e < 8; e++)
          B.u[e] = bf16u(sm.d.xs[(48 + q * 8 + e) * 36 + nt * 16 + r]);
        f4 acc = {0.f, 0.f, 0.f, 0.f};
        acc = __builtin_amdgcn_mfma_f32_16x16x32_bf16(af, B.v, acc, 0, 0, 0);
        int n = n0 + nt * 16 + r;
        f4* dst = reinterpret_cast<f4*>(
            Bt + ((size_t)b * NN + n) * 64 + w * 16 + q * 4);
        *dst = acc;
      }
    }
    __syncthreads();
    if (n0 + 32 > 1008) {
      for (int idx = t; idx < 80 * 16; idx += 256) {
        int row = idx >> 4, col = 16 + (idx & 15);
        sm.d.xs[row * 36 + col] = 0.f;
      }
    }
    __syncthreads();
    float* gp = Gp + ((size_t)(b * 32 + ct)) * 1024;
    for (int e = t; e < 1024; e += 256) {
      int mat = e >> 9, r = (e >> 4) & 31, i = e & 15;
      const f4* xr = reinterpret_cast<const f4*>(&sm.d.xs[(16 + mat * 32 + r) * 36]);
      const f4* xi = reinterpret_cast<const f4*>(&sm.d.xs[i * 36]);
      float s = 0.f;
      #pragma unroll
      for (int cq = 0; cq < 8; cq++) {
        f4 a = xr[cq], bq = xi[cq];
        s += a[0]*bq[0] + a[1]*bq[1] + a[2]*bq[2] + a[3]*bq[3];
      }
      gp[e] = s;
    }
  } else {
    int a = blockIdx.x - 1024;
    int b = a >> 4;
    int mg = a & 15;
    const float* xb = x + (size_t)b * DINR * NN;
    #pragma unroll
    for (int rep = 0; rep < 4; rep++) {
      int n = t + (rep << 8);
      unsigned int pk[8];
      #pragma unroll
      for (int h = 0; h < 8; h++) {
        unsigned int u0 = __float_as_uint(xb[(2*h) * NN + n]);
        unsigned int u1 = __float_as_uint(xb[(2*h+1) * NN + n]);
        pk[h] = (u0 >> 16) | (u1 & 0xFFFF0000u);
      }
      #pragma unroll
      for (int h = 0; h < 8; h++) sm.XT[n * 8 + h] = pk[h];
    }
    __syncthreads();
    int w = t >> 6;
    int lane = t & 63;
    int r = lane & 15;
    int g = lane >> 4;
    int mt = mg * 64 + w * 16;
    s8 zero8 = {0,0,0,0,0,0,0,0};
    s8 afrag = zero8;
    if (g < 2) afrag = *reinterpret_cast<const s8*>(&sm.XT[(mt + r) * 8 + g * 4]);
    float bestv[4];
    int besti[4];
    #pragma unroll
    for (int j = 0; j < 4; j++) { bestv[j] = -3.4e38f; besti[j] = 0x7FFFFFFF; }
    for (int nt = 0; nt < 63; nt++) {
      s8 bfrag = zero8;
      if (g < 2) bfrag = *reinterpret_cast<const s8*>(&sm.XT[(nt*16 + r) * 8 + g * 4]);
      f4 acc = {0.f, 0.f, 0.f, 0.f};
      acc = __builtin_amdgcn_mfma_f32_16x16x32_bf16(afrag, bfrag, acc, 0, 0, 0);
      int n = nt * 16 + r;
      #pragma unroll
      for (int j = 0; j < 4; j++) {
        float v = acc[j];
        bool better = (v > bestv[j]) || (v == bestv[j] && n < besti[j]);
        if (better) { bestv[j] = v; besti[j] = n; }
      }
    }
    #pragma unroll
    for (int s = 1; s < 16; s <<= 1) {
      #pragma unroll
      for (int j = 0; j < 4; j++) {
        float ov = __shfl_xor(bestv[j], s, 64);
        int   oi = __shfl_xor(besti[j], s, 64);
        bool better = (ov > bestv[j]) || (ov == bestv[j] && oi < besti[j]);
        if (better) { bestv[j] = ov; besti[j] = oi; }
      }
    }
    if (r == 0) {
      #pragma unroll
      for (int j = 0; j < 4; j++)
        nstar[b * NN + mt + g * 4 + j] = besti[j];
    }
  }
}

// ---------------------------------------------------------------------------
// k_comb: Uc[j][i] = alpha_l[j] * ( E[j][:]·G[:,i] − SB[j][i] )
//   ncb==0: G = Σct(G2−G3), SB=0 (layer 0). else G=ΣctG2, SB=Σ_{ch<ncb} Up
//   FIX R13: Up batch stride is ncb*1024 (was hardcoded 32*1024)
// ---------------------------------------------------------------------------
__global__ __launch_bounds__(256) void k_comb(
    const float* __restrict__ Gp, const float* __restrict__ Up, int ncb,
    const float* __restrict__ emb, const float* __restrict__ alpha, int l,
    float* __restrict__ Uc)
{
  __shared__ float G[512];
  int b = blockIdx.x >> 2;
  int qd = blockIdx.x & 3;
  int t = threadIdx.x;
  for (int e = t; e < 512; e += 256) {
    const float* p2 = Gp + (size_t)b * 32 * 1024 + e;
    float s = 0.f;
    #pragma unroll 8
    for (int ct = 0; ct < 32; ct++) s += p2[ct * 1024];
    if (ncb == 0) {
      const float* p3 = p2 + 512;
      float s3 = 0.f;
      #pragma unroll 8
      for (int ct = 0; ct < 32; ct++) s3 += p3[ct * 1024];
      s -= s3;
    }
    G[e] = s;
  }
  __syncthreads();
  int e = qd * 256 + t;
  int j = e >> 4, i = e & 15;
  const float* Er = emb + j * 32;
  float acc = 0.f;
  #pragma unroll
  for (int r = 0; r < 32; r++) acc = fmaf(Er[r], G[r * 16 + i], acc);
  float sb = 0.f;
  if (ncb > 0) {
    const float* pb = Up + (size_t)b * ncb * 1024 + e;   // FIX: ncb stride
    for (int ch = 0; ch < ncb; ch++) sb += pb[ch * 1024];
  }
  Uc[(size_t)b * 1024 + e] = alpha[l * 64 + j] * (acc - sb);
}

// ---------------------------------------------------------------------------
// k_update (MFMA rewrite, R12 body unchanged): 256 thr / 4 waves, grid 512.
// ---------------------------------------------------------------------------
__global__ __launch_bounds__(256) void k_update(
    const float* __restrict__ x, const float* __restrict__ emb,
    const float* __restrict__ kpp, const float* __restrict__ Uc,
    const int* __restrict__ nstar,
    const float* __restrict__ Cin, size_t cbs, float* __restrict__ Cout,
    const float* __restrict__ Bin, float* __restrict__ Bout,
    float* __restrict__ Upout, int last, float* __restrict__ out)
{
  __shared__ unsigned short Us[64 * 24];   // U bf16 [j][i], stride 24
  __shared__ unsigned short Xt[64 * 24];   // X^T bf16 [col][i], stride 24
  __shared__ unsigned short Xb[16 * 72];   // X bf16 [i][col], stride 72
  __shared__ unsigned short Et[32 * 72];   // E^T bf16 [cat][j], stride 72
  __shared__ unsigned short Eb[64 * 40];   // E bf16 [j][cat], stride 40
  __shared__ unsigned short Cb[64 * 72];   // C' bf16 [col][j], stride 72
  __shared__ unsigned short Ps[64 * 40];   // p bf16 [col][cat], stride 40
  __shared__ unsigned short Wsh[64 * 72];  // w bf16 [j][col], stride 72
  int t = threadIdx.x;
  int b = blockIdx.x >> 4;
  int mt = blockIdx.x & 15;
  int n0 = mt * 64;
  int lane = t & 63, w = t >> 6;
  int r = lane & 15, q = lane >> 4;
  const float* xb = x + (size_t)b * DINR * NN;

  // ---- staging ----
  for (int idx = t; idx < 512; idx += 256) {       // Us
    int j = idx >> 3, i2 = (idx & 7) * 2;
    const float* u = Uc + (size_t)b * 1024 + j * 16 + i2;
    unsigned int pk = (unsigned int)bf16u(u[0]) | ((unsigned int)bf16u(u[1]) << 16);
    *reinterpret_cast<unsigned int*>(&Us[j * 24 + i2]) = pk;
  }
  for (int e = t; e < 2048; e += 256) {            // Et, Eb
    int j = e >> 5, cat = e & 31;
    unsigned short v = bf16u(emb[e]);
    Eb[j * 40 + cat] = v;
    Et[cat * 72 + j] = v;
  }
  for (int e = t; e < 1024; e += 256) {            // Xb, Xt
    int i = e >> 6, col = e & 63;
    unsigned short v = bf16u(xb[i * NN + n0 + col]);
    Xb[i * 72 + col] = v;
    Xt[col * 24 + i] = v;
  }
  __syncthreads();

  float sc = kpp[0] * (1.0f / 1008.0f);
  int mcol = n0 + w * 16 + r;                      // this lane's column
  s8 zero8 = {0, 0, 0, 0, 0, 0, 0, 0};

  // ---- GEMM1: C' = Cin + sc*(U@X); write Cout (f32) + Cb (bf16) ----
  {
    s8 bx = zero8;
    if (q < 2) bx = *reinterpret_cast<const s8*>(&Xt[(w * 16 + r) * 24 + q * 8]);
    #pragma unroll
    for (int jt = 0; jt < 4; jt++) {
      s8 au = zero8;
      if (q < 2) au = *reinterpret_cast<const s8*>(&Us[(jt * 16 + r) * 24 + q * 8]);
      f4 acc = {0.f, 0.f, 0.f, 0.f};
      acc = __builtin_amdgcn_mfma_f32_16x16x32_bf16(au, bx, acc, 0, 0, 0);
      float cn[4];
      #pragma unroll
      for (int reg = 0; reg < 4; reg++) {
        int j = jt * 16 + q * 4 + reg;
        float ci = Cin[(size_t)b * cbs + (size_t)j * NN + mcol];
        cn[reg] = ci + sc * acc[reg];
        if (!last) Cout[(size_t)b * 64 * NN + (size_t)j * NN + mcol] = cn[reg];
      }
      unsigned int u0 = (unsigned int)bf16u(cn[0]) | ((unsigned int)bf16u(cn[1]) << 16);
      unsigned int u1 = (unsigned int)bf16u(cn[2]) | ((unsigned int)bf16u(cn[3]) << 16);
      unsigned int base = (w * 16 + r) * 72 + jt * 16 + q * 4;
      *reinterpret_cast<unsigned int*>(&Cb[base]) = u0;
      *reinterpret_cast<unsigned int*>(&Cb[base + 2]) = u1;
    }
  }

  // ---- GEMM2: S = Et @ Cb (wave-local Cb rows) ----
  f4 sacc[2] = {{0.f,0.f,0.f,0.f}, {0.f,0.f,0.f,0.f}};
  #pragma unroll
  for (int ct = 0; ct < 2; ct++) {
    #pragma unroll
    for (int kt = 0; kt < 2; kt++) {
      s8 ae = *reinterpret_cast<const s8*>(&Et[(ct * 16 + r) * 72 + kt * 32 + q * 8]);
      s8 bc = *reinterpret_cast<const s8*>(&Cb[(w * 16 + r) * 72 + kt * 32 + q * 8]);
      sacc[ct] = __builtin_amdgcn_mfma_f32_16x16x32_bf16(ae, bc, sacc[ct], 0, 0, 0);
    }
  }

  // ---- softmax over 32 cats of column mcol ----
  float p[2][4];
  float mx = -3.4e38f;
  #pragma unroll
  for (int ct = 0; ct < 2; ct++)
    #pragma unroll
    for (int reg = 0; reg < 4; reg++) mx = fmaxf(mx, sacc[ct][reg]);
  mx = fmaxf(mx, __shfl_xor(mx, 16, 64));
  mx = fmaxf(mx, __shfl_xor(mx, 32, 64));
  float ss = 0.f;
  #pragma unroll
  for (int ct = 0; ct < 2; ct++)
    #pragma unroll
    for (int reg = 0; reg < 4; reg++) {
      p[ct][reg] = __expf(sacc[ct][reg] - mx);
      ss += p[ct][reg];
    }
  ss += __shfl_xor(ss, 16, 64);
  ss += __shfl_xor(ss, 32, 64);
  float inv = 1.0f / ss;
  #pragma unroll
  for (int ct = 0; ct < 2; ct++)
    #pragma unroll
    for (int reg = 0; reg < 4; reg++) p[ct][reg] *= inv;

  if (last) {
    float* lo = out + ((size_t)b * NN + mcol) * 32;
    float* po = lo + (size_t)NB * NN * 32;
    #pragma unroll
    for (int ct = 0; ct < 2; ct++) {
      f4 vl = {sacc[ct][0], sacc[ct][1], sacc[ct][2], sacc[ct][3]};
      f4 vp = {p[ct][0], p[ct][1], p[ct][2], p[ct][3]};
      *reinterpret_cast<f4*>(lo + ct * 16 + q * 4) = vl;
      *reinterpret_cast<f4*>(po + ct * 16 + q * 4) = vp;
    }
    return;
  }

  // ---- p -> Ps (wave-local) ----
  #pragma unroll
  for (int ct = 0; ct < 2; ct++) {
    unsigned int u0 = (unsigned int)bf16u(p[ct][0]) | ((unsigned int)bf16u(p[ct][1]) << 16);
    unsigned int u1 = (unsigned int)bf16u(p[ct][2]) | ((unsigned int)bf16u(p[ct][3]) << 16);
    unsigned int base = (w * 16 + r) * 40 + ct * 16 + q * 4;
    *reinterpret_cast<unsigned int*>(&Ps[base]) = u0;
    *reinterpret_cast<unsigned int*>(&Ps[base + 2]) = u1;
  }

  // ---- GEMM3: Ep = Eb @ Ps ----
  f4 eacc[4];
  {
    s8 bp = *reinterpret_cast<const s8*>(&Ps[(w * 16 + r) * 40 + q * 8]);
    #pragma unroll
    for (int jt = 0; jt < 4; jt++) {
      s8 ae = *reinterpret_cast<const s8*>(&Eb[(jt * 16 + r) * 40 + q * 8]);
      f4 z = {0.f, 0.f, 0.f, 0.f};
      eacc[jt] = __builtin_amdgcn_mfma_f32_16x16x32_bf16(ae, bp, z, 0, 0, 0);
    }
  }

  // ---- B update ----
  float vv[4][4];
  {
    int nst = nstar[b * NN + mcol];
    const f4* BC = reinterpret_cast<const f4*>(Bin + ((size_t)b * NN + mcol) * 64);
    const f4* BG = reinterpret_cast<const f4*>(Bin + ((size_t)b * NN + nst) * 64);
    f4* BO = reinterpret_cast<f4*>(Bout + ((size_t)b * NN + mcol) * 64);
    const float invM = 1.0f / 1008.0f;
    #pragma unroll
    for (int jt = 0; jt < 4; jt++) {
      f4 bc4 = BC[jt * 4 + q];
      f4 bg4 = BG[jt * 4 + q];
      f4 vo;
      #pragma unroll
      for (int reg = 0; reg < 4; reg++) {
        vo[reg] = bc4[reg] - bg4[reg] * invM + eacc[jt][reg];
        vv[jt][reg] = vo[reg];
      }
      BO[jt * 4 + q] = vo;
    }
  }

  // ---- w -> Wsh (masked), cross-wave ----
  {
    bool live = (mcol < 1008);
    #pragma unroll
    for (int jt = 0; jt < 4; jt++)
      #pragma unroll
      for (int reg = 0; reg < 4; reg++)
        Wsh[(jt * 16 + q * 4 + reg) * 72 + (w * 16 + r)] =
            live ? bf16u(vv[jt][reg]) : (unsigned short)0;
  }
  __syncthreads();

  // ---- GEMM4: Up = w @ X^T (wave w -> j-tile w) ----
  {
    f4 uacc = {0.f, 0.f, 0.f, 0.f};
    #pragma unroll
    for (int kt = 0; kt < 2; kt++) {
      s8 aw = *reinterpret_cast<const s8*>(&Wsh[(w * 16 + r) * 72 + kt * 32 + q * 8]);
      s8 bxx = *reinterpret_cast<const s8*>(&Xb[r * 72 + kt * 32 + q * 8]);
      uacc = __builtin_amdgcn_mfma_f32_16x16x32_bf16(aw, bxx, uacc, 0, 0, 0);
    }
    float* upb = Upout + ((size_t)(b * 16 + mt)) * 1024;
    #pragma unroll
    for (int reg = 0; reg < 4; reg++)
      upb[(w * 16 + q * 4 + reg) * 16 + r] = uacc[reg];
  }
}

extern "C" void kernel_launch(void* const* d_in, const int* in_sizes, int n_in,
                              void* d_out, int out_size, void* d_ws, size_t ws_size,
                              hipStream_t stream)
{
  const float* x     = (const float*)d_in[0];
  const float* alpha = (const float*)d_in[1];
  const float* kp    = (const float*)d_in[2];
  const float* emb   = (const float*)d_in[3];
  float* ws = (float*)d_ws;
  float* B0  = ws + OFF_B0;
  float* B1  = ws + OFF_B1;
  float* C   = ws + OFF_C;
  float* UpA = ws + OFF_UPA;
  float* UpB = ws + OFF_UPB;
  float* Gp  = ws + OFF_GP;
  float* Uc  = ws + OFF_UC;
  int*   ns  = (int*)(ws + OFF_NS);
  float* out = (float*)d_out;

  k_init<<<1536, 256, 0, stream>>>(x, emb, B0, Gp, ns);
  // layer 0: Uc = alpha(E@(G2-G3)); Cin = x[80:144]; B0->B1; Up -> UpA (16 ch)
  k_comb<<<128, 256, 0, stream>>>(Gp, UpA, 0, emb, alpha, 0, Uc);
  k_update<<<512, 256, 0, stream>>>(x, emb, kp, Uc, ns,
                                    x + 80 * NN, (size_t)DINR * NN, C,
                                    B0, B1, UpA, 0, out);
  // layer 1: Uc = alpha(E@G2 - sum UpA); B1->B0; -> UpB
  k_comb<<<128, 256, 0, stream>>>(Gp, UpA, 16, emb, alpha, 1, Uc);
  k_update<<<512, 256, 0, stream>>>(x, emb, kp, Uc, ns,
                                    C, (size_t)64 * NN, C,
                                    B1, B0, UpB, 0, out);
  // layer 2 (last): Uc = alpha(E@G2 - sum UpB); outputs only
  k_comb<<<128, 256, 0, stream>>>(Gp, UpB, 16, emb, alpha, 2, Uc);
  k_update<<<512, 256, 0, stream>>>(x, emb, kp, Uc, ns,
                                    C, (size_t)64 * NN, C,
                                    B0, B1, UpA, 1, out);
}

// Round 16
// 83.816 us; speedup vs baseline: 2.5495x; 1.1114x over previous
//
#include <hip/hip_runtime.h>
#include <hip/hip_bf16.h>

#define NB 32
#define NN 1024
#define DINR 144

typedef __attribute__((ext_vector_type(4))) float f4;
typedef __attribute__((ext_vector_type(8))) short s8;

// ws float offsets
#define OFF_B0   (0u)                          // bf16 [32][1024][64] -> 1M floats
#define OFF_B1   (1048576u)
#define OFF_S0   (2097152u)                    // f32 [32][32][1024]
#define OFF_UPA  (3145728u)                    // f32 [32][16][1024]
#define OFF_UPB  (3670016u)
#define OFF_GP   (4194304u)                    // f32 [32][32][1024]
#define OFF_UCUM (5242880u)                    // f32 [32][1024]
#define OFF_V    (5275648u)                    // f32 [32][512]
#define OFF_NS   (5292032u)

static __device__ __forceinline__ unsigned short bf16u(float f) {
  __hip_bfloat16 h = __float2bfloat16(f);
  return *reinterpret_cast<unsigned short*>(&h);
}
static __device__ __forceinline__ float bfu2f(unsigned int u16) {
  unsigned int v = u16 << 16;
  return __uint_as_float(v);
}

// ---------------------------------------------------------------------------
// k_init
//  blocks [0,1024): b=blk>>5, ct=blk&31 (32-col slab):
//    stage x rows 0..143 + E; B0 = E@x3 (bf16 col-major, MFMA);
//    S0 = E^T @ x[80:144] (f32, MFMA); Gram partials G2,G3 (masked) -> Gp
//  blocks [1024,1536): nstar = argmax_{n<1008} X[:,m]·X[:,n]  (bf16 MFMA)
// ---------------------------------------------------------------------------
__global__ __launch_bounds__(256) void k_init(
    const float* __restrict__ x, const float* __restrict__ emb,
    unsigned short* __restrict__ Bt, float* __restrict__ Gp,
    float* __restrict__ S0, int* __restrict__ nstar)
{
  __shared__ union {
    unsigned int XT[NN * 8];                   // 32768 B (argmax part)
    struct {
      float xs[144 * 36];                      // 20736 B
      unsigned int Eb[64 * 16];                // 4096 B (E rows, bf16 pairs)
      unsigned short etr[32 * 72];             // 4608 B (E^T, bf16)
    } d;
  } sm;
  int t = threadIdx.x;
  if (blockIdx.x < 1024) {
    int b = blockIdx.x >> 5;
    int ct = blockIdx.x & 31;
    int n0 = ct * 32;
    const float* xb = x + (size_t)b * DINR * NN;
    for (int idx = t; idx < 144 * 32; idx += 256) {
      int row = idx >> 5, col = idx & 31;
      sm.d.xs[row * 36 + col] = xb[row * NN + n0 + col];
    }
    for (int e = t; e < 1024; e += 256) {
      int j = e >> 4, hp = e & 15;
      float f0 = emb[j * 32 + hp * 2];
      float f1 = emb[j * 32 + hp * 2 + 1];
      sm.d.Eb[j * 16 + hp] =
          (unsigned int)bf16u(f0) | ((unsigned int)bf16u(f1) << 16);
    }
    for (int e = t; e < 2048; e += 256) {
      int j = e >> 5, cat = e & 31;
      sm.d.etr[cat * 72 + j] = bf16u(emb[e]);
    }
    __syncthreads();
    int lane = t & 63, w = t >> 6;
    int r = lane & 15, q = lane >> 4;
    // B0 = E @ x3 (A = E rows, K=32), bf16 col-major write
    {
      s8 af = *reinterpret_cast<const s8*>(&sm.d.Eb[(w * 16 + r) * 16 + q * 4]);
      #pragma unroll
      for (int nt = 0; nt < 2; nt++) {
        union { s8 v; unsigned short u[8]; } B;
        #pragma unroll
        for (int e = 0; e < 8; e++)
          B.u[e] = bf16u(sm.d.xs[(48 + q * 8 + e) * 36 + nt * 16 + r]);
        f4 acc = {0.f, 0.f, 0.f, 0.f};
        acc = __builtin_amdgcn_mfma_f32_16x16x32_bf16(af, B.v, acc, 0, 0, 0);
        int n = n0 + nt * 16 + r;
        unsigned int p0 = (unsigned int)bf16u(acc[0]) | ((unsigned int)bf16u(acc[1]) << 16);
        unsigned int p1 = (unsigned int)bf16u(acc[2]) | ((unsigned int)bf16u(acc[3]) << 16);
        unsigned int* dst = reinterpret_cast<unsigned int*>(
            Bt + ((size_t)b * NN + n) * 64 + w * 16 + q * 4);
        dst[0] = p0; dst[1] = p1;
      }
    }
    // S0 = E^T @ C0 (C0 = x rows 80..143), K=64 = 2 MFMA steps
    {
      int mt = w & 1;     // cat tile
      int nt = w >> 1;    // col tile
      f4 acc = {0.f, 0.f, 0.f, 0.f};
      #pragma unroll
      for (int kt = 0; kt < 2; kt++) {
        s8 ae = *reinterpret_cast<const s8*>(&sm.d.etr[(mt * 16 + r) * 72 + kt * 32 + q * 8]);
        union { s8 v; unsigned short u[8]; } Bx;
        #pragma unroll
        for (int e = 0; e < 8; e++)
          Bx.u[e] = bf16u(sm.d.xs[(80 + kt * 32 + q * 8 + e) * 36 + nt * 16 + r]);
        acc = __builtin_amdgcn_mfma_f32_16x16x32_bf16(ae, Bx.v, acc, 0, 0, 0);
      }
      #pragma unroll
      for (int reg = 0; reg < 4; reg++)
        S0[(size_t)b * 32 * NN + (size_t)(mt * 16 + q * 4 + reg) * NN + n0 + nt * 16 + r] = acc[reg];
    }
    __syncthreads();
    // mask dead columns (slab containing n>=1008): zero X/x2/x3 rows 0..79
    if (n0 + 32 > 1008) {
      for (int idx = t; idx < 80 * 16; idx += 256) {
        int row = idx >> 4, col = 16 + (idx & 15);
        sm.d.xs[row * 36 + col] = 0.f;
      }
    }
    __syncthreads();
    // Gram partials: 1024 entries (mat,r,i)
    float* gp = Gp + ((size_t)(b * 32 + ct)) * 1024;
    for (int e = t; e < 1024; e += 256) {
      int mat = e >> 9, rr = (e >> 4) & 31, i = e & 15;
      const f4* xr = reinterpret_cast<const f4*>(&sm.d.xs[(16 + mat * 32 + rr) * 36]);
      const f4* xi = reinterpret_cast<const f4*>(&sm.d.xs[i * 36]);
      float s = 0.f;
      #pragma unroll
      for (int cq = 0; cq < 8; cq++) {
        f4 a = xr[cq], bq = xi[cq];
        s += a[0]*bq[0] + a[1]*bq[1] + a[2]*bq[2] + a[3]*bq[3];
      }
      gp[e] = s;
    }
  } else {
    int a = blockIdx.x - 1024;
    int b = a >> 4;
    int mg = a & 15;
    const float* xb = x + (size_t)b * DINR * NN;
    #pragma unroll
    for (int rep = 0; rep < 4; rep++) {
      int n = t + (rep << 8);
      unsigned int pk[8];
      #pragma unroll
      for (int h = 0; h < 8; h++) {
        unsigned int u0 = __float_as_uint(xb[(2*h) * NN + n]);
        unsigned int u1 = __float_as_uint(xb[(2*h+1) * NN + n]);
        pk[h] = (u0 >> 16) | (u1 & 0xFFFF0000u);
      }
      #pragma unroll
      for (int h = 0; h < 8; h++) sm.XT[n * 8 + h] = pk[h];
    }
    __syncthreads();
    int w = t >> 6;
    int lane = t & 63;
    int r = lane & 15;
    int g = lane >> 4;
    int mt = mg * 64 + w * 16;
    s8 zero8 = {0,0,0,0,0,0,0,0};
    s8 afrag = zero8;
    if (g < 2) afrag = *reinterpret_cast<const s8*>(&sm.XT[(mt + r) * 8 + g * 4]);
    float bestv[4];
    int besti[4];
    #pragma unroll
    for (int j = 0; j < 4; j++) { bestv[j] = -3.4e38f; besti[j] = 0x7FFFFFFF; }
    for (int nt = 0; nt < 63; nt++) {
      s8 bfrag = zero8;
      if (g < 2) bfrag = *reinterpret_cast<const s8*>(&sm.XT[(nt*16 + r) * 8 + g * 4]);
      f4 acc = {0.f, 0.f, 0.f, 0.f};
      acc = __builtin_amdgcn_mfma_f32_16x16x32_bf16(afrag, bfrag, acc, 0, 0, 0);
      int n = nt * 16 + r;
      #pragma unroll
      for (int j = 0; j < 4; j++) {
        float v = acc[j];
        bool better = (v > bestv[j]) || (v == bestv[j] && n < besti[j]);
        if (better) { bestv[j] = v; besti[j] = n; }
      }
    }
    #pragma unroll
    for (int s = 1; s < 16; s <<= 1) {
      #pragma unroll
      for (int j = 0; j < 4; j++) {
        float ov = __shfl_xor(bestv[j], s, 64);
        int   oi = __shfl_xor(besti[j], s, 64);
        bool better = (ov > bestv[j]) || (ov == bestv[j] && oi < besti[j]);
        if (better) { bestv[j] = ov; besti[j] = oi; }
      }
    }
    if (r == 0) {
      #pragma unroll
      for (int j = 0; j < 4; j++)
        nstar[b * NN + mt + g * 4 + j] = besti[j];
    }
  }
}

// ---------------------------------------------------------------------------
// k_comb (32 blocks x 512 thr): Uc_l = alpha_l ∘ (E@G − SB);
//   Ucum += Uc_l (l==0: Ucum = Uc_0);  V = E^T @ Ucum (32x16)
// ---------------------------------------------------------------------------
__global__ __launch_bounds__(512) void k_comb(
    const float* __restrict__ Gp, const float* __restrict__ Up, int ncb,
    const float* __restrict__ emb, const float* __restrict__ alpha, int l,
    float* __restrict__ Ucum, float* __restrict__ V)
{
  __shared__ float G[512];
  __shared__ float Uc[1024];
  int b = blockIdx.x;
  int t = threadIdx.x;
  if (t < 512) {
    const float* p2 = Gp + (size_t)b * 32 * 1024 + t;
    float s = 0.f;
    #pragma unroll 8
    for (int ct = 0; ct < 32; ct++) s += p2[ct * 1024];
    if (ncb == 0) {
      const float* p3 = p2 + 512;
      float s3 = 0.f;
      #pragma unroll 8
      for (int ct = 0; ct < 32; ct++) s3 += p3[ct * 1024];
      s -= s3;
    }
    G[t] = s;
  }
  __syncthreads();
  for (int e = t; e < 1024; e += 512) {
    int j = e >> 4, i = e & 15;
    const float* Er = emb + j * 32;
    float acc = 0.f;
    #pragma unroll
    for (int r = 0; r < 32; r++) acc = fmaf(Er[r], G[r * 16 + i], acc);
    float sb = 0.f;
    if (ncb > 0) {
      const float* pb = Up + (size_t)b * ncb * 1024 + e;
      for (int ch = 0; ch < ncb; ch++) sb += pb[ch * 1024];
    }
    float uc = alpha[l * 64 + j] * (acc - sb);
    float prev = (l == 0) ? 0.f : Ucum[(size_t)b * 1024 + e];
    float nc = prev + uc;
    Ucum[(size_t)b * 1024 + e] = nc;
    Uc[e] = nc;
  }
  __syncthreads();
  if (t < 512) {
    int cat = t >> 4, i = t & 15;
    float acc = 0.f;
    #pragma unroll
    for (int j = 0; j < 64; j++) acc = fmaf(emb[j * 32 + cat], Uc[j * 16 + i], acc);
    V[(size_t)b * 512 + t] = acc;
  }
}

// ---------------------------------------------------------------------------
// k_update: logits = S0 + sc*(V@X) [1 MFMA pair]; softmax; B-update (bf16 B);
//   Up = w @ X^T (MFMA). 256 thr / 4 waves, grid 512 = 32 b x 16 tiles.
// ---------------------------------------------------------------------------
__global__ __launch_bounds__(256) void k_update(
    const float* __restrict__ x, const float* __restrict__ emb,
    const float* __restrict__ kpp, const float* __restrict__ V,
    const float* __restrict__ S0, const int* __restrict__ nstar,
    const unsigned short* __restrict__ Bin, unsigned short* __restrict__ Bout,
    float* __restrict__ Upout, int last, float* __restrict__ out)
{
  __shared__ unsigned short Xt[64 * 24];   // X^T bf16 [col][i]
  __shared__ unsigned short Xb[16 * 72];   // X bf16 [i][col]
  __shared__ unsigned short Vs[32 * 24];   // V bf16 [cat][i]
  __shared__ unsigned short Eb[64 * 40];   // E bf16 [j][cat]
  __shared__ unsigned short Ps[64 * 40];   // p bf16 [col][cat]
  __shared__ unsigned short Wsh[64 * 72];  // w bf16 [j][col]
  int t = threadIdx.x;
  int b = blockIdx.x >> 4;
  int mt = blockIdx.x & 15;
  int n0 = mt * 64;
  int lane = t & 63, w = t >> 6;
  int r = lane & 15, q = lane >> 4;
  const float* xb = x + (size_t)b * DINR * NN;

  for (int e = t; e < 1024; e += 256) {
    int i = e >> 6, col = e & 63;
    unsigned short v = bf16u(xb[i * NN + n0 + col]);
    Xb[i * 72 + col] = v;
    Xt[col * 24 + i] = v;
  }
  for (int e = t; e < 2048; e += 256) {
    int j = e >> 5, cat = e & 31;
    Eb[j * 40 + cat] = bf16u(emb[e]);
  }
  for (int e = t; e < 512; e += 256) {
    Vs[(e >> 4) * 24 + (e & 15)] = bf16u(V[(size_t)b * 512 + e]);
  }
  __syncthreads();

  float sc = kpp[0] * (1.0f / 1008.0f);
  int mcol = n0 + w * 16 + r;
  s8 zero8 = {0, 0, 0, 0, 0, 0, 0, 0};

  // ---- logits = S0 + sc*(V@X): M=32 cat, N=16 col (this wave), K=16 ----
  f4 sacc[2];
  {
    s8 bx = zero8;
    if (q < 2) bx = *reinterpret_cast<const s8*>(&Xt[(w * 16 + r) * 24 + q * 8]);
    #pragma unroll
    for (int ct = 0; ct < 2; ct++) {
      s8 av = zero8;
      if (q < 2) av = *reinterpret_cast<const s8*>(&Vs[(ct * 16 + r) * 24 + q * 8]);
      f4 z = {0.f, 0.f, 0.f, 0.f};
      f4 mm = __builtin_amdgcn_mfma_f32_16x16x32_bf16(av, bx, z, 0, 0, 0);
      #pragma unroll
      for (int reg = 0; reg < 4; reg++) {
        int cat = ct * 16 + q * 4 + reg;
        sacc[ct][reg] = S0[(size_t)b * 32 * NN + (size_t)cat * NN + mcol] + sc * mm[reg];
      }
    }
  }

  // ---- softmax over 32 cats of column mcol ----
  float p[2][4];
  float mx = -3.4e38f;
  #pragma unroll
  for (int ct = 0; ct < 2; ct++)
    #pragma unroll
    for (int reg = 0; reg < 4; reg++) mx = fmaxf(mx, sacc[ct][reg]);
  mx = fmaxf(mx, __shfl_xor(mx, 16, 64));
  mx = fmaxf(mx, __shfl_xor(mx, 32, 64));
  float ss = 0.f;
  #pragma unroll
  for (int ct = 0; ct < 2; ct++)
    #pragma unroll
    for (int reg = 0; reg < 4; reg++) {
      p[ct][reg] = __expf(sacc[ct][reg] - mx);
      ss += p[ct][reg];
    }
  ss += __shfl_xor(ss, 16, 64);
  ss += __shfl_xor(ss, 32, 64);
  float inv = 1.0f / ss;
  #pragma unroll
  for (int ct = 0; ct < 2; ct++)
    #pragma unroll
    for (int reg = 0; reg < 4; reg++) p[ct][reg] *= inv;

  if (last) {
    float* lo = out + ((size_t)b * NN + mcol) * 32;
    float* po = lo + (size_t)NB * NN * 32;
    #pragma unroll
    for (int ct = 0; ct < 2; ct++) {
      f4 vl = {sacc[ct][0], sacc[ct][1], sacc[ct][2], sacc[ct][3]};
      f4 vp = {p[ct][0], p[ct][1], p[ct][2], p[ct][3]};
      *reinterpret_cast<f4*>(lo + ct * 16 + q * 4) = vl;
      *reinterpret_cast<f4*>(po + ct * 16 + q * 4) = vp;
    }
    return;
  }

  // ---- p -> Ps (wave-local) ----
  #pragma unroll
  for (int ct = 0; ct < 2; ct++) {
    unsigned int u0 = (unsigned int)bf16u(p[ct][0]) | ((unsigned int)bf16u(p[ct][1]) << 16);
    unsigned int u1 = (unsigned int)bf16u(p[ct][2]) | ((unsigned int)bf16u(p[ct][3]) << 16);
    unsigned int base = (w * 16 + r) * 40 + ct * 16 + q * 4;
    *reinterpret_cast<unsigned int*>(&Ps[base]) = u0;
    *reinterpret_cast<unsigned int*>(&Ps[base + 2]) = u1;
  }

  // ---- GEMM3: Ep = Eb @ Ps ----
  f4 eacc[4];
  {
    s8 bp = *reinterpret_cast<const s8*>(&Ps[(w * 16 + r) * 40 + q * 8]);
    #pragma unroll
    for (int jt = 0; jt < 4; jt++) {
      s8 ae = *reinterpret_cast<const s8*>(&Eb[(jt * 16 + r) * 40 + q * 8]);
      f4 z = {0.f, 0.f, 0.f, 0.f};
      eacc[jt] = __builtin_amdgcn_mfma_f32_16x16x32_bf16(ae, bp, z, 0, 0, 0);
    }
  }

  // ---- B update (bf16 B, col-major [n][64]) ----
  float vv[4][4];
  {
    int nst = nstar[b * NN + mcol];
    const unsigned int* BC = reinterpret_cast<const unsigned int*>(
        Bin + ((size_t)b * NN + mcol) * 64);
    const unsigned int* BG = reinterpret_cast<const unsigned int*>(
        Bin + ((size_t)b * NN + nst) * 64);
    unsigned int* BO = reinterpret_cast<unsigned int*>(
        Bout + ((size_t)b * NN + mcol) * 64);
    const float invM = 1.0f / 1008.0f;
    #pragma unroll
    for (int jt = 0; jt < 4; jt++) {
      unsigned int c0 = BC[jt * 8 + q * 2], c1 = BC[jt * 8 + q * 2 + 1];
      unsigned int g0 = BG[jt * 8 + q * 2], g1 = BG[jt * 8 + q * 2 + 1];
      float bc[4] = { bfu2f(c0 & 0xFFFFu), bfu2f(c0 >> 16),
                      bfu2f(c1 & 0xFFFFu), bfu2f(c1 >> 16) };
      float bg[4] = { bfu2f(g0 & 0xFFFFu), bfu2f(g0 >> 16),
                      bfu2f(g1 & 0xFFFFu), bfu2f(g1 >> 16) };
      float vo[4];
      #pragma unroll
      for (int reg = 0; reg < 4; reg++) {
        vo[reg] = bc[reg] - bg[reg] * invM + eacc[jt][reg];
        vv[jt][reg] = vo[reg];
      }
      BO[jt * 8 + q * 2]     = (unsigned int)bf16u(vo[0]) | ((unsigned int)bf16u(vo[1]) << 16);
      BO[jt * 8 + q * 2 + 1] = (unsigned int)bf16u(vo[2]) | ((unsigned int)bf16u(vo[3]) << 16);
    }
  }

  // ---- w -> Wsh (masked), cross-wave ----
  {
    bool live = (mcol < 1008);
    #pragma unroll
    for (int jt = 0; jt < 4; jt++)
      #pragma unroll
      for (int reg = 0; reg < 4; reg++)
        Wsh[(jt * 16 + q * 4 + reg) * 72 + (w * 16 + r)] =
            live ? bf16u(vv[jt][reg]) : (unsigned short)0;
  }
  __syncthreads();

  // ---- GEMM4: Up = w @ X^T (wave w -> j-tile w) ----
  {
    f4 uacc = {0.f, 0.f, 0.f, 0.f};
    #pragma unroll
    for (int kt = 0; kt < 2; kt++) {
      s8 aw = *reinterpret_cast<const s8*>(&Wsh[(w * 16 + r) * 72 + kt * 32 + q * 8]);
      s8 bxx = *reinterpret_cast<const s8*>(&Xb[r * 72 + kt * 32 + q * 8]);
      uacc = __builtin_amdgcn_mfma_f32_16x16x32_bf16(aw, bxx, uacc, 0, 0, 0);
    }
    float* upb = Upout + ((size_t)(b * 16 + mt)) * 1024;
    #pragma unroll
    for (int reg = 0; reg < 4; reg++)
      upb[(w * 16 + q * 4 + reg) * 16 + r] = uacc[reg];
  }
}

extern "C" void kernel_launch(void* const* d_in, const int* in_sizes, int n_in,
                              void* d_out, int out_size, void* d_ws, size_t ws_size,
                              hipStream_t stream)
{
  const float* x     = (const float*)d_in[0];
  const float* alpha = (const float*)d_in[1];
  const float* kp    = (const float*)d_in[2];
  const float* emb   = (const float*)d_in[3];
  float* ws = (float*)d_ws;
  unsigned short* B0u = (unsigned short*)(ws + OFF_B0);
  unsigned short* B1u = (unsigned short*)(ws + OFF_B1);
  float* S0   = ws + OFF_S0;
  float* UpA  = ws + OFF_UPA;
  float* UpB  = ws + OFF_UPB;
  float* Gp   = ws + OFF_GP;
  float* Ucum = ws + OFF_UCUM;
  float* Vb   = ws + OFF_V;
  int*   ns   = (int*)(ws + OFF_NS);
  float* out  = (float*)d_out;

  k_init<<<1536, 256, 0, stream>>>(x, emb, B0u, Gp, S0, ns);
  // layer 0
  k_comb<<<32, 512, 0, stream>>>(Gp, UpA, 0, emb, alpha, 0, Ucum, Vb);
  k_update<<<512, 256, 0, stream>>>(x, emb, kp, Vb, S0, ns,
                                    B0u, B1u, UpA, 0, out);
  // layer 1
  k_comb<<<32, 512, 0, stream>>>(Gp, UpA, 16, emb, alpha, 1, Ucum, Vb);
  k_update<<<512, 256, 0, stream>>>(x, emb, kp, Vb, S0, ns,
                                    B1u, B0u, UpB, 0, out);
  // layer 2 (last): outputs only
  k_comb<<<32, 512, 0, stream>>>(Gp, UpB, 16, emb, alpha, 2, Ucum, Vb);
  k_update<<<512, 256, 0, stream>>>(x, emb, kp, Vb, S0, ns,
                                    B0u, B1u, UpA, 1, out);
}